// Round 3
// baseline (3131.069 us; speedup 1.0000x reference)
//
#include <hip/hip_runtime.h>
#include <stdint.h>

#define B_   4096
#define S_   544
#define H_   256
#define D_   128
#define M_   50000
#define KNN  50
#define NSLICE 16
#define SLICE_LEN (M_ / NSLICE)   // 3125
#define CAP  76
#define TN   128                  // keys per k3 tile

typedef unsigned long long u64;
typedef unsigned int u32;

// ---------------- K1: h = relu(states@W1+b1) (z=0), v1 = relu(states@V1+c1) (z=1) ----
__global__ __launch_bounds__(256) void k1_gemm(
    const float* __restrict__ A,
    const float* __restrict__ W1, const float* __restrict__ b1,
    const float* __restrict__ V1, const float* __restrict__ c1,
    float* __restrict__ hout, float* __restrict__ v1out)
{
  const float* W    = (blockIdx.z == 0) ? W1 : V1;
  const float* bias = (blockIdx.z == 0) ? b1 : c1;
  float* out        = (blockIdx.z == 0) ? hout : v1out;

  __shared__ float as[16][68];
  __shared__ float bs[16][64];

  int tid = threadIdx.x;
  int tx = tid & 15, ty = tid >> 4;
  int rb = blockIdx.y * 64, cb = blockIdx.x * 64;

  float acc[4][4] = {};

  for (int k0 = 0; k0 < S_; k0 += 16) {
    {
      int r = tid >> 2, k4 = (tid & 3) << 2;
      float4 a = *(const float4*)&A[(size_t)(rb + r) * S_ + k0 + k4];
      as[k4 + 0][r] = a.x; as[k4 + 1][r] = a.y;
      as[k4 + 2][r] = a.z; as[k4 + 3][r] = a.w;
    }
    {
      int kk = tid >> 4, c4 = (tid & 15) << 2;
      *(float4*)&bs[kk][c4] = *(const float4*)&W[(size_t)(k0 + kk) * H_ + cb + c4];
    }
    __syncthreads();
#pragma unroll
    for (int kk = 0; kk < 16; ++kk) {
      float4 a4 = *(const float4*)&as[kk][ty << 2];
      float4 b4 = *(const float4*)&bs[kk][tx << 2];
      float av[4] = {a4.x, a4.y, a4.z, a4.w};
      float bv[4] = {b4.x, b4.y, b4.z, b4.w};
#pragma unroll
      for (int i = 0; i < 4; ++i)
#pragma unroll
        for (int j = 0; j < 4; ++j)
          acc[i][j] = fmaf(av[i], bv[j], acc[i][j]);
    }
    __syncthreads();
  }

#pragma unroll
  for (int i = 0; i < 4; ++i) {
    int r = rb + (ty << 2) + i;
#pragma unroll
    for (int j = 0; j < 4; ++j) {
      int c = cb + (tx << 2) + j;
      float v = acc[i][j] + bias[c];
      out[(size_t)r * H_ + c] = v > 0.0f ? v : 0.0f;
    }
  }
}

// ---------------- K2: mode 0: qT[d][b] = LN(h@W2+b2)^T, q2 = sum(q*q)
//                      mode 1: v2 = relu(v1@V2+c2); net = v2@V3 + c3 ------------------
__global__ __launch_bounds__(256) void k2_fused(
    int mode,
    const float* __restrict__ A,      // [B_][H_]
    const float* __restrict__ W,      // [H_][D_]
    const float* __restrict__ bias,   // [D_]
    const float* __restrict__ lng, const float* __restrict__ lnb,
    const float* __restrict__ V3, const float* __restrict__ c3,
    float* __restrict__ qTout, float* __restrict__ q2out,
    float* __restrict__ netout)
{
  __shared__ float as[32][36];
  __shared__ float bs[32][132];
  __shared__ float yt[32][132];
  __shared__ float v3s[128];

  int tid = threadIdx.x;
  int tx = tid & 31, ty = tid >> 5;
  int rb = blockIdx.x * 32;

  if (mode == 1 && tid < 128) v3s[tid] = V3[tid];

  float acc[4][4] = {};

  for (int k0 = 0; k0 < H_; k0 += 32) {
    {
      int r = tid >> 3, k4 = (tid & 7) << 2;
      float4 a = *(const float4*)&A[(size_t)(rb + r) * H_ + k0 + k4];
      as[k4 + 0][r] = a.x; as[k4 + 1][r] = a.y;
      as[k4 + 2][r] = a.z; as[k4 + 3][r] = a.w;
    }
    {
      int kk = tid >> 3, c16 = (tid & 7) << 4;
#pragma unroll
      for (int t = 0; t < 4; ++t)
        *(float4*)&bs[kk][c16 + (t << 2)] =
            *(const float4*)&W[(size_t)(k0 + kk) * D_ + c16 + (t << 2)];
    }
    __syncthreads();
#pragma unroll
    for (int kk = 0; kk < 32; ++kk) {
      float4 a4 = *(const float4*)&as[kk][ty << 2];
      float4 b4 = *(const float4*)&bs[kk][tx << 2];
      float av[4] = {a4.x, a4.y, a4.z, a4.w};
      float bv[4] = {b4.x, b4.y, b4.z, b4.w};
#pragma unroll
      for (int i = 0; i < 4; ++i)
#pragma unroll
        for (int j = 0; j < 4; ++j)
          acc[i][j] = fmaf(av[i], bv[j], acc[i][j]);
    }
    __syncthreads();
  }

#pragma unroll
  for (int i = 0; i < 4; ++i)
#pragma unroll
    for (int j = 0; j < 4; ++j) {
      int c = (tx << 2) + j;
      yt[(ty << 2) + i][c] = acc[i][j] + bias[c];
    }
  __syncthreads();

  int r8 = tid >> 3, j8 = tid & 7;
  int rg = rb + r8;
  if (mode == 0) {
    float s = 0.f;
#pragma unroll
    for (int t = 0; t < 16; ++t) s += yt[r8][(j8 << 4) + t];
    s += __shfl_xor(s, 1); s += __shfl_xor(s, 2); s += __shfl_xor(s, 4);
    float mu = s * (1.0f / 128.0f);
    float vs = 0.f;
#pragma unroll
    for (int t = 0; t < 16; ++t) {
      float d = yt[r8][(j8 << 4) + t] - mu;
      vs = fmaf(d, d, vs);
    }
    vs += __shfl_xor(vs, 1); vs += __shfl_xor(vs, 2); vs += __shfl_xor(vs, 4);
    float var = vs * (1.0f / 128.0f);
    float rstd = 1.0f / sqrtf(var + 1e-5f);
    float q2p = 0.f;
#pragma unroll
    for (int t = 0; t < 16; ++t) {
      int c = (j8 << 4) + t;
      float qv = (yt[r8][c] - mu) * rstd * lng[c] + lnb[c];
      qTout[(size_t)c * B_ + rg] = qv;            // transposed store
      q2p = fmaf(qv, qv, q2p);
    }
    q2p += __shfl_xor(q2p, 1); q2p += __shfl_xor(q2p, 2); q2p += __shfl_xor(q2p, 4);
    if (j8 == 0) q2out[rg] = q2p;
  } else {
    float s = 0.f;
#pragma unroll
    for (int t = 0; t < 16; ++t) {
      int c = (j8 << 4) + t;
      float v = yt[r8][c];
      v = v > 0.f ? v : 0.f;
      s = fmaf(v, v3s[c], s);
    }
    s += __shfl_xor(s, 1); s += __shfl_xor(s, 2); s += __shfl_xor(s, 4);
    if (j8 == 0) netout[rg] = s + c3[0];
  }
}

// ---------------- K0: k2[m] = sum_d mem_keys[m][d]^2 ---------------------------------
__global__ __launch_bounds__(256) void k0_keynorm(
    const float* __restrict__ keys, float* __restrict__ k2out)
{
  int m = blockIdx.x * 8 + (threadIdx.x >> 5);
  int l = threadIdx.x & 31;
  float4 a = *(const float4*)&keys[(size_t)m * D_ + (l << 2)];
  float s = a.x * a.x + a.y * a.y + a.z * a.z + a.w * a.w;
  s += __shfl_xor(s, 1); s += __shfl_xor(s, 2); s += __shfl_xor(s, 4);
  s += __shfl_xor(s, 8); s += __shfl_xor(s, 16);
  if (l == 0) k2out[m] = s;
}

// ---------------- K3: fused distance GEMM + per-(row,slice) exact top-50 -------------
__device__ __forceinline__ void sort128_wave(u64* sb, int lane) {
  for (int k = 2; k <= 128; k <<= 1)
    for (int j = k >> 1; j > 0; j >>= 1) {
#pragma unroll
      for (int half = 0; half < 2; ++half) {
        int e = lane + (half << 6);
        int p = e ^ j;
        if (p > e) {
          u64 x = sb[e], y = sb[p];
          bool up = ((e & k) == 0);
          if ((x > y) == up) { sb[e] = y; sb[p] = x; }
        }
      }
      __builtin_amdgcn_wave_barrier();
    }
}

// 4 waves, each handles 16 rows
__device__ void compact_block(
    bool final_, int rb, int slice, int tid,
    u64 (*sortbuf)[128], u64* thresh, int* cnt, u64* lbuf)
{
  int w = tid >> 6, lane = tid & 63;
  for (int rr = 0; rr < 16; ++rr) {
    int r = (w << 4) + rr;
    int c0 = cnt[r];
    if (!final_ && c0 <= CAP) continue;     // trigger only on overflow
    int valid = c0 < CAP ? c0 : CAP;
    u64* gb = &lbuf[(((size_t)(rb + r)) * NSLICE + slice) * CAP];
    u64 e0 = (lane < valid) ? gb[lane] : ~0ULL;
    u64 e1 = (lane + 64 < valid) ? gb[lane + 64] : ~0ULL;
    u64* sb = sortbuf[w];
    sb[lane] = e0; sb[lane + 64] = e1;
    __builtin_amdgcn_wave_barrier();
    sort128_wave(sb, lane);
    __builtin_amdgcn_wave_barrier();
    if (lane < KNN) gb[lane] = sb[lane];
    if (lane == 0) { cnt[r] = KNN; thresh[r] = sb[KNN - 1]; }
    __builtin_amdgcn_wave_barrier();
  }
}

__global__ __launch_bounds__(256, 4) void k3_knn(
    const float* __restrict__ qT,     // [D_][B_] transposed queries
    const float* __restrict__ q2g,
    const float* __restrict__ keys, const float* __restrict__ k2g,
    u64* __restrict__ lbuf)
{
  __shared__ float ks[64][132];     // d-chunk x keys, stride 132 (16B-aligned rows)
  __shared__ u64 sortbuf[4][128];
  __shared__ u64 thresh[64];
  __shared__ int cnt[64];
  __shared__ float q2s[64];
  __shared__ int ovf;

  int tid = threadIdx.x;
  int lin = blockIdx.x;
  int slice = lin & 15;             // consecutive blocks -> different slices -> XCD-pinned
  int rb = (lin >> 4) << 6;
  int m_start = slice * SLICE_LEN;
  int m_end = m_start + SLICE_LEN;

  if (tid < 64) {
    q2s[tid] = q2g[rb + tid];
    thresh[tid] = ~0ULL;
    cnt[tid] = 0;
  }
  if (tid == 0) ovf = 0;

  int tx = tid & 31, ty = tid >> 5;   // tx: 4 keys, ty: 8 rows
  int r0 = ty << 3;

  // staging ids: key sm (0..127), d-offset sd (0 or 32)
  int sm = tid >> 1;
  int sd = (tid & 1) << 5;

  const int NSTEP = 2 * ((SLICE_LEN + TN - 1) / TN);   // 50

  float4 pf[8];
  // prologue: load + write chunk for step 0 (tile 0, db 0)
  {
    int mg = m_start + sm; if (mg > m_end - 1) mg = m_end - 1;
    const float* kp = &keys[(size_t)mg * D_ + sd];
#pragma unroll
    for (int t = 0; t < 8; ++t) pf[t] = *(const float4*)(kp + (t << 2));
  }
#pragma unroll
  for (int t = 0; t < 8; ++t) {
    int d = sd + (t << 2);
    ks[d + 0][sm] = pf[t].x; ks[d + 1][sm] = pf[t].y;
    ks[d + 2][sm] = pf[t].z; ks[d + 3][sm] = pf[t].w;
  }
  __syncthreads();

  float acc[8][4] = {};

  for (int s = 0; s < NSTEP; ++s) {
    int tile = s >> 1, db = (s & 1) << 6;
    int t0 = m_start + tile * TN;

    // (a) prefetch next step's chunk into registers (T14 issue-early)
    if (s + 1 < NSTEP) {
      int nt = (s + 1) >> 1, ndb = ((s + 1) & 1) << 6;
      int t0n = m_start + nt * TN;
      int mg = t0n + sm; if (mg > m_end - 1) mg = m_end - 1;
      const float* kp = &keys[(size_t)mg * D_ + ndb + sd];
#pragma unroll
      for (int t = 0; t < 8; ++t) pf[t] = *(const float4*)(kp + (t << 2));
    }

    // (b) compute: 64 kk, 8 rows x 4 keys per thread
    {
      const float* qp = qT + (size_t)db * B_ + rb + r0;
#pragma unroll 4
      for (int kk = 0; kk < 64; ++kk) {
        float4 qa = *(const float4*)qp;
        float4 qb = *(const float4*)(qp + 4);
        float4 b4 = *(const float4*)&ks[kk][tx << 2];
        float qv[8] = {qa.x, qa.y, qa.z, qa.w, qb.x, qb.y, qb.z, qb.w};
        float bv[4] = {b4.x, b4.y, b4.z, b4.w};
#pragma unroll
        for (int i = 0; i < 8; ++i)
#pragma unroll
          for (int j = 0; j < 4; ++j)
            acc[i][j] = fmaf(qv[i], bv[j], acc[i][j]);
        qp += B_;
      }
    }

    __syncthreads();            // (c) all waves done reading ks

    if (s + 1 < NSTEP) {        // (d) write-late: next chunk into LDS
#pragma unroll
      for (int t = 0; t < 8; ++t) {
        int d = sd + (t << 2);
        ks[d + 0][sm] = pf[t].x; ks[d + 1][sm] = pf[t].y;
        ks[d + 2][sm] = pf[t].z; ks[d + 3][sm] = pf[t].w;
      }
    }
    __syncthreads();            // (e) writes visible

    if (s & 1) {
      // ---- selection for completed tile ----
      float k2v[4];
      u32 pend = 0;
#pragma unroll
      for (int j = 0; j < 4; ++j) {
        int c = (tx << 2) + j;
        if (t0 + c < m_end) {
          k2v[j] = k2g[t0 + c];
#pragma unroll
          for (int i = 0; i < 8; ++i) pend |= (1u << ((i << 2) | j));
        } else k2v[j] = 0.f;
      }

      for (;;) {
        if (tid == 0) ovf = 0;
        __syncthreads();
        if (pend) {
#pragma unroll
          for (int i = 0; i < 8; ++i) {
            int r = r0 + i;
            float q2v = q2s[r];
#pragma unroll
            for (int j = 0; j < 4; ++j) {
              u32 bit = 1u << ((i << 2) | j);
              if (pend & bit) {
                int c = (tx << 2) + j;
                float dd = q2v + k2v[j] - 2.0f * acc[i][j];
                u64 ck = ((u64)__float_as_uint(dd) << 32) | (u32)(t0 + c);
                if (ck < thresh[r]) {
                  int pos = atomicAdd(&cnt[r], 1);
                  if (pos < CAP) {
                    lbuf[(((size_t)(rb + r)) * NSLICE + slice) * CAP + pos] = ck;
                    pend &= ~bit;
                  } else {
                    ovf = 1;      // benign race: all writers store 1
                  }
                } else pend &= ~bit;
              }
            }
          }
        }
        __syncthreads();
        if (!ovf) break;
        __threadfence_block();
        compact_block(false, rb, slice, tid, sortbuf, thresh, cnt, lbuf);
        __syncthreads();
      }

#pragma unroll
      for (int i = 0; i < 8; ++i)
#pragma unroll
        for (int j = 0; j < 4; ++j) acc[i][j] = 0.f;
    }
  }

  __threadfence_block();
  compact_block(true, rb, slice, tid, sortbuf, thresh, cnt, lbuf);
}

// ---------------- K4: merge 16x50 per-slice winners -> exact top-50 -> output --------
__global__ __launch_bounds__(64) void k4_merge(
    const u64* __restrict__ lbuf, const float* __restrict__ memv,
    const float* __restrict__ net, float* __restrict__ out)
{
  __shared__ u64 sb[1024];
  int b = blockIdx.x, l = threadIdx.x;
#pragma unroll
  for (int h = 0; h < 16; ++h) {
    int e = l + (h << 6);
    u64 v = ~0ULL;
    if (e < NSLICE * KNN) {
      int s = e / KNN, j = e - s * KNN;
      v = lbuf[((size_t)b * NSLICE + s) * CAP + j];
    }
    sb[e] = v;
  }
  __builtin_amdgcn_wave_barrier();
  for (int k = 2; k <= 1024; k <<= 1)
    for (int j = k >> 1; j > 0; j >>= 1) {
#pragma unroll
      for (int h = 0; h < 16; ++h) {
        int e = l + (h << 6);
        int p = e ^ j;
        if (p > e) {
          u64 x = sb[e], y = sb[p];
          bool up = ((e & k) == 0);
          if ((x > y) == up) { sb[e] = y; sb[p] = x; }
        }
      }
      __builtin_amdgcn_wave_barrier();
    }
  __builtin_amdgcn_wave_barrier();
  float w = 0.f, wv = 0.f;
  if (l < KNN) {
    u64 key = sb[l];
    float d = __uint_as_float((u32)(key >> 32));
    u32 idx = (u32)key;
    float ww = 1.0f / (d + 1e-7f);
    w = ww;
    wv = ww * memv[idx];
  }
#pragma unroll
  for (int o = 1; o < 64; o <<= 1) {
    w += __shfl_xor(w, o);
    wv += __shfl_xor(wv, o);
  }
  if (l == 0) out[b] = 0.9f * (wv / w) + 0.1f * net[b];
}

// ---------------- launch --------------------------------------------------------------
extern "C" void kernel_launch(void* const* d_in, const int* in_sizes, int n_in,
                              void* d_out, int out_size, void* d_ws, size_t ws_size,
                              hipStream_t stream)
{
  const float* states     = (const float*)d_in[0];
  const float* W1         = (const float*)d_in[1];
  const float* b1         = (const float*)d_in[2];
  const float* W2         = (const float*)d_in[3];
  const float* b2         = (const float*)d_in[4];
  const float* lng        = (const float*)d_in[5];
  const float* lnb        = (const float*)d_in[6];
  const float* mem_keys   = (const float*)d_in[7];
  const float* mem_values = (const float*)d_in[8];
  const float* V1         = (const float*)d_in[9];
  const float* c1         = (const float*)d_in[10];
  const float* V2         = (const float*)d_in[11];
  const float* c2         = (const float*)d_in[12];
  const float* V3         = (const float*)d_in[13];
  const float* c3         = (const float*)d_in[14];
  float* out = (float*)d_out;

  char* ws = (char*)d_ws;
  float* qT  = (float*)(ws + 0);            // 2 MB   [D_][B_]
  float* q2  = (float*)(ws + 2097152);      // 16 KB
  float* net = (float*)(ws + 2113536);      // 16 KB
  float* k2g = (float*)(ws + 2129920);      // 200 KB
  u64*  lbuf = (u64*)(ws + 2359296);        // 4096*16*76*8 = 39.85 MB (ends ~42.2 MB)
  // h / v1 overlay the lbuf region: both are dead before k3 writes lbuf
  float* h   = (float*)(ws + 2359296);            // 4 MB
  float* v1  = (float*)(ws + 2359296 + 4194304);  // 4 MB

  k1_gemm<<<dim3(H_ / 64, B_ / 64, 2), 256, 0, stream>>>(states, W1, b1, V1, c1, h, v1);
  k2_fused<<<dim3(B_ / 32), 256, 0, stream>>>(0, h, W2, b2, lng, lnb, V3, c3, qT, q2, net);
  k2_fused<<<dim3(B_ / 32), 256, 0, stream>>>(1, v1, V2, c2, lng, lnb, V3, c3, qT, q2, net);
  k0_keynorm<<<dim3(M_ / 8), 256, 0, stream>>>(mem_keys, k2g);
  k3_knn<<<dim3((B_ / 64) * NSLICE), 256, 0, stream>>>(qT, q2, mem_keys, k2g, lbuf);
  k4_merge<<<dim3(B_), 64, 0, stream>>>(lbuf, mem_values, net, out);
}

// Round 4
// 1828.928 us; speedup vs baseline: 1.7120x; 1.7120x over previous
//
#include <hip/hip_runtime.h>
#include <stdint.h>

#define B_   4096
#define S_   544
#define H_   256
#define D_   128
#define M_   50000
#define KNN  50
#define NSLICE 8
#define SLICE_LEN (M_ / NSLICE)   // 6250
#define CAP  88
#define TN   128                  // keys per k3 tile
#define NT   ((SLICE_LEN + TN - 1) / TN)   // 49
#define RR   64                   // rerank count

typedef unsigned long long u64;
typedef unsigned int u32;
typedef __attribute__((ext_vector_type(8))) __bf16 bf16x8;
typedef __attribute__((ext_vector_type(4))) float f32x4;
typedef __attribute__((ext_vector_type(4))) u32 u32x4;

__device__ __forceinline__ u32 bf16_rne(float x) {
  u32 u = __float_as_uint(x);
  return (u + 0x7FFFu + ((u >> 16) & 1u)) >> 16;
}
__device__ __forceinline__ void split_bf16(float x, u32& hi, u32& lo) {
  hi = bf16_rne(x);
  float hif = __uint_as_float(hi << 16);
  lo = bf16_rne(x - hif);
}

// ---------------- K1: h = relu(states@W1+b1) (z=0), v1 = relu(states@V1+c1) (z=1) ----
__global__ __launch_bounds__(256) void k1_gemm(
    const float* __restrict__ A,
    const float* __restrict__ W1, const float* __restrict__ b1,
    const float* __restrict__ V1, const float* __restrict__ c1,
    float* __restrict__ hout, float* __restrict__ v1out)
{
  const float* W    = (blockIdx.z == 0) ? W1 : V1;
  const float* bias = (blockIdx.z == 0) ? b1 : c1;
  float* out        = (blockIdx.z == 0) ? hout : v1out;

  __shared__ float as[16][68];
  __shared__ float bs[16][64];

  int tid = threadIdx.x;
  int tx = tid & 15, ty = tid >> 4;
  int rb = blockIdx.y * 64, cb = blockIdx.x * 64;

  float acc[4][4] = {};

  for (int k0 = 0; k0 < S_; k0 += 16) {
    {
      int r = tid >> 2, k4 = (tid & 3) << 2;
      float4 a = *(const float4*)&A[(size_t)(rb + r) * S_ + k0 + k4];
      as[k4 + 0][r] = a.x; as[k4 + 1][r] = a.y;
      as[k4 + 2][r] = a.z; as[k4 + 3][r] = a.w;
    }
    {
      int kk = tid >> 4, c4 = (tid & 15) << 2;
      *(float4*)&bs[kk][c4] = *(const float4*)&W[(size_t)(k0 + kk) * H_ + cb + c4];
    }
    __syncthreads();
#pragma unroll
    for (int kk = 0; kk < 16; ++kk) {
      float4 a4 = *(const float4*)&as[kk][ty << 2];
      float4 b4 = *(const float4*)&bs[kk][tx << 2];
      float av[4] = {a4.x, a4.y, a4.z, a4.w};
      float bv[4] = {b4.x, b4.y, b4.z, b4.w};
#pragma unroll
      for (int i = 0; i < 4; ++i)
#pragma unroll
        for (int j = 0; j < 4; ++j)
          acc[i][j] = fmaf(av[i], bv[j], acc[i][j]);
    }
    __syncthreads();
  }

#pragma unroll
  for (int i = 0; i < 4; ++i) {
    int r = rb + (ty << 2) + i;
#pragma unroll
    for (int j = 0; j < 4; ++j) {
      int c = cb + (tx << 2) + j;
      float v = acc[i][j] + bias[c];
      out[(size_t)r * H_ + c] = v > 0.0f ? v : 0.0f;
    }
  }
}

// ---------------- K2: mode 0: q = LN(h@W2+b2) -> qrow(f32), qext(split bf16), q2
//                      mode 1: v2 = relu(v1@V2+c2); net = v2@V3 + c3 ------------------
__global__ __launch_bounds__(256) void k2_fused(
    int mode,
    const float* __restrict__ A,      // [B_][H_]
    const float* __restrict__ W,      // [H_][D_]
    const float* __restrict__ bias,   // [D_]
    const float* __restrict__ lng, const float* __restrict__ lnb,
    const float* __restrict__ V3, const float* __restrict__ c3,
    u32* __restrict__ qext, float* __restrict__ qrow,
    float* __restrict__ q2out, float* __restrict__ netout)
{
  __shared__ float as[32][36];
  __shared__ float bs[32][132];
  __shared__ float yt[32][132];
  __shared__ float v3s[128];

  int tid = threadIdx.x;
  int tx = tid & 31, ty = tid >> 5;
  int rb = blockIdx.x * 32;

  if (mode == 1 && tid < 128) v3s[tid] = V3[tid];

  float acc[4][4] = {};

  for (int k0 = 0; k0 < H_; k0 += 32) {
    {
      int r = tid >> 3, k4 = (tid & 7) << 2;
      float4 a = *(const float4*)&A[(size_t)(rb + r) * H_ + k0 + k4];
      as[k4 + 0][r] = a.x; as[k4 + 1][r] = a.y;
      as[k4 + 2][r] = a.z; as[k4 + 3][r] = a.w;
    }
    {
      int kk = tid >> 3, c16 = (tid & 7) << 4;
#pragma unroll
      for (int t = 0; t < 4; ++t)
        *(float4*)&bs[kk][c16 + (t << 2)] =
            *(const float4*)&W[(size_t)(k0 + kk) * D_ + c16 + (t << 2)];
    }
    __syncthreads();
#pragma unroll
    for (int kk = 0; kk < 32; ++kk) {
      float4 a4 = *(const float4*)&as[kk][ty << 2];
      float4 b4 = *(const float4*)&bs[kk][tx << 2];
      float av[4] = {a4.x, a4.y, a4.z, a4.w};
      float bv[4] = {b4.x, b4.y, b4.z, b4.w};
#pragma unroll
      for (int i = 0; i < 4; ++i)
#pragma unroll
        for (int j = 0; j < 4; ++j)
          acc[i][j] = fmaf(av[i], bv[j], acc[i][j]);
    }
    __syncthreads();
  }

#pragma unroll
  for (int i = 0; i < 4; ++i)
#pragma unroll
    for (int j = 0; j < 4; ++j) {
      int c = (tx << 2) + j;
      yt[(ty << 2) + i][c] = acc[i][j] + bias[c];
    }
  __syncthreads();

  int r8 = tid >> 3, j8 = tid & 7;
  int rg = rb + r8;
  if (mode == 0) {
    float s = 0.f;
#pragma unroll
    for (int t = 0; t < 16; ++t) s += yt[r8][(j8 << 4) + t];
    s += __shfl_xor(s, 1); s += __shfl_xor(s, 2); s += __shfl_xor(s, 4);
    float mu = s * (1.0f / 128.0f);
    float vs = 0.f;
#pragma unroll
    for (int t = 0; t < 16; ++t) {
      float d = yt[r8][(j8 << 4) + t] - mu;
      vs = fmaf(d, d, vs);
    }
    vs += __shfl_xor(vs, 1); vs += __shfl_xor(vs, 2); vs += __shfl_xor(vs, 4);
    float var = vs * (1.0f / 128.0f);
    float rstd = 1.0f / sqrtf(var + 1e-5f);
    float q2p = 0.f;
    ushort* qe = (ushort*)qext + (size_t)rg * 256;
#pragma unroll
    for (int t = 0; t < 16; ++t) {
      int c = (j8 << 4) + t;
      float qv = (yt[r8][c] - mu) * rstd * lng[c] + lnb[c];
      qrow[(size_t)rg * D_ + c] = qv;
      u32 hi, lo; split_bf16(qv, hi, lo);
      int ii = ((c >> 5) << 5) + (c & 31);
      qe[ii] = (ushort)hi;
      qe[128 + ii] = (ushort)lo;
      q2p = fmaf(qv, qv, q2p);
    }
    q2p += __shfl_xor(q2p, 1); q2p += __shfl_xor(q2p, 2); q2p += __shfl_xor(q2p, 4);
    if (j8 == 0) q2out[rg] = q2p;
  } else {
    float s = 0.f;
#pragma unroll
    for (int t = 0; t < 16; ++t) {
      int c = (j8 << 4) + t;
      float v = yt[r8][c];
      v = v > 0.f ? v : 0.f;
      s = fmaf(v, v3s[c], s);
    }
    s += __shfl_xor(s, 1); s += __shfl_xor(s, 2); s += __shfl_xor(s, 4);
    if (j8 == 0) netout[rg] = s + c3[0];
  }
}

// ---------------- K5: keys -> split bf16 ext [M][128 u32] + exact k2 norms ------------
__global__ __launch_bounds__(256) void k5_keyext(
    const float* __restrict__ keys, u32* __restrict__ keyext,
    float* __restrict__ k2out)
{
  int t = threadIdx.x;
  int m = blockIdx.x * 64 + (t >> 2);
  int sub = t & 3;
  if (m >= M_) return;
  const float* kp = &keys[(size_t)m * D_ + sub * 32];
  u32 hw[16], lw[16];
  float ss = 0.f;
#pragma unroll
  for (int i = 0; i < 8; ++i) {
    float4 x = *(const float4*)(kp + i * 4);
    ss = fmaf(x.x, x.x, fmaf(x.y, x.y, fmaf(x.z, x.z, fmaf(x.w, x.w, ss))));
    u32 h0,l0,h1,l1,h2,l2,h3,l3;
    split_bf16(x.x,h0,l0); split_bf16(x.y,h1,l1);
    split_bf16(x.z,h2,l2); split_bf16(x.w,h3,l3);
    hw[i*2]   = h0 | (h1<<16); hw[i*2+1] = h2 | (h3<<16);
    lw[i*2]   = l0 | (l1<<16); lw[i*2+1] = l2 | (l3<<16);
  }
  u32* rp = keyext + (size_t)m * 128;
#pragma unroll
  for (int i = 0; i < 4; ++i) {
    *(u32x4*)(rp + sub*16 + i*4)      = *(const u32x4*)(hw + i*4);
    *(u32x4*)(rp + 64 + sub*16 + i*4) = *(const u32x4*)(lw + i*4);
  }
  ss += __shfl_xor(ss, 1); ss += __shfl_xor(ss, 2);
  if (sub == 0) k2out[m] = ss;
}

// ---------------- K3 helpers: per-(row,slice) streaming top-50 on u32 keys ------------
__device__ __forceinline__ void sort128_wave(u32* sb, int lane) {
  for (int k = 2; k <= 128; k <<= 1)
    for (int j = k >> 1; j > 0; j >>= 1) {
#pragma unroll
      for (int half = 0; half < 2; ++half) {
        int e = lane + (half << 6);
        int p = e ^ j;
        if (p > e) {
          u32 x = sb[e], y = sb[p];
          bool up = ((e & k) == 0);
          if ((x > y) == up) { sb[e] = y; sb[p] = x; }
        }
      }
      __builtin_amdgcn_wave_barrier();
    }
}

__device__ void compact_block(
    bool final_, int rb, int slice, int tid,
    u32 (*sortbuf)[128], u32* thresh, int* cnt, u32* lbuf)
{
  int w = tid >> 6, lane = tid & 63;
  for (int rr = 0; rr < 16; ++rr) {
    int r = (w << 4) | rr;
    int c0 = cnt[r];
    if (!final_ && c0 <= CAP) continue;     // trigger only on overflow
    int valid = c0 < CAP ? c0 : CAP;
    u32* gb = &lbuf[(((size_t)(rb + r)) * NSLICE + slice) * CAP];
    u32 e0 = (lane < valid) ? gb[lane] : 0xFFFFFFFFu;
    u32 e1 = (lane + 64 < valid) ? gb[lane + 64] : 0xFFFFFFFFu;
    u32* sb = sortbuf[w];
    sb[lane] = e0; sb[lane + 64] = e1;
    __builtin_amdgcn_wave_barrier();
    sort128_wave(sb, lane);
    __builtin_amdgcn_wave_barrier();
    if (lane < KNN) gb[lane] = sb[lane];
    if (lane == 0) { cnt[r] = KNN; thresh[r] = sb[KNN - 1]; }
    __builtin_amdgcn_wave_barrier();
  }
}

// ---------------- K3: split-bf16 MFMA distance GEMM + approx top-50 -------------------
__global__ __launch_bounds__(256) void k3_knn(
    const u32* __restrict__ qext,    // [B_][128] u32 (512B rows: 4 hi chunks, 4 lo)
    const float* __restrict__ q2g,
    const u32* __restrict__ keyext,  // [M_][128] u32
    const float* __restrict__ k2g,
    u32* __restrict__ lbuf)
{
  __shared__ u32 kbuf[2][2048];     // 2 x 8KB key chunk (128 keys x 32 k bf16, swizzled)
  __shared__ u32 sortbuf[4][128];
  __shared__ u32 thresh[64];
  __shared__ int cnt[64];
  __shared__ float q2s[64];
  __shared__ int ovf;

  int tid = threadIdx.x;
  int lane = tid & 63;
  int w = tid >> 6;
  int wr = w >> 1, wc = w & 1;      // 2x2 wave grid: 32 rows x 64 keys per wave
  int slice = blockIdx.x & 7;       // consecutive blocks -> different slices/XCDs
  int rb = (blockIdx.x >> 3) << 6;
  int m0 = slice * SLICE_LEN;
  int mmax = m0 + SLICE_LEN - 1;

  if (tid < 64) { q2s[tid] = q2g[rb + tid]; thresh[tid] = 0xFFFFFFFFu; cnt[tid] = 0; }
  if (tid == 0) ovf = 0;

  // ---- A fragments (q_ext) in registers for the whole kernel ----
  bf16x8 afr[2][8];
  {
    int kg = lane >> 4;
#pragma unroll
    for (int fr = 0; fr < 2; ++fr) {
      const u32* qp = qext + (size_t)(rb + wr * 32 + fr * 16 + (lane & 15)) * 128 + kg * 4;
#pragma unroll
      for (int ca = 0; ca < 8; ++ca)
        afr[fr][ca] = __builtin_bit_cast(bf16x8, *(const u32x4*)(qp + ca * 16));
    }
  }

  // staging decode (2 x 16B slots per thread), swizzled: slot s of pair-row pr
  // holds key (2pr + (u>>2)), k-16B-group (u&3), where u = s ^ (pr&7)
  int skey[2], skoff[2], sdst[2];
  {
    int s = lane & 7, l3 = lane >> 3;
    int u = s ^ l3;                   // pr&7 == l3 for both i
#pragma unroll
    for (int i = 0; i < 2; ++i) {
      int pr = w * 16 + i * 8 + l3;
      skey[i] = pr * 2 + (u >> 2);
      skoff[i] = (u & 3) * 4;         // u32 units
      sdst[i] = pr * 32 + s * 4;      // u32 units
    }
  }

  u32x4 pf[2];
  auto issue = [&](int tile_, int cb_) {
#pragma unroll
    for (int i = 0; i < 2; ++i) {
      int m = m0 + tile_ * TN + skey[i]; if (m > mmax) m = mmax;
      pf[i] = *(const u32x4*)(keyext + (size_t)m * 128 + cb_ * 16 + skoff[i]);
    }
  };

  issue(0, 0);
  { *(u32x4*)&kbuf[0][sdst[0]] = pf[0]; *(u32x4*)&kbuf[0][sdst[1]] = pf[1]; }
  __syncthreads();

  f32x4 acc[2][4] = {};
  int cur = 0;

  for (int tile = 0; tile < NT; ++tile) {
    int t0l = tile * TN;
#pragma unroll 1
    for (int ph = 0; ph < 12; ++ph) {
      bool more = !(tile == NT - 1 && ph == 11);
      if (more) {
        int nph = (ph == 11) ? 0 : ph + 1;
        int ntile = (ph == 11) ? tile + 1 : tile;
        int ncb = (nph < 8) ? nph : nph - 8;
        issue(ntile, ncb);
      }
      int ca = (ph < 4) ? ph : ph - 4;
#pragma unroll
      for (int fc = 0; fc < 4; ++fc) {
        int key = wc * 64 + fc * 16 + (lane & 15);
        int j = lane >> 4;
        int pr = key >> 1;
        int s = (((key & 1) << 2) | j) ^ (pr & 7);
        bf16x8 b = __builtin_bit_cast(bf16x8, *(const u32x4*)&kbuf[cur][pr * 32 + s * 4]);
        acc[0][fc] = __builtin_amdgcn_mfma_f32_16x16x32_bf16(afr[0][ca], b, acc[0][fc], 0, 0, 0);
        acc[1][fc] = __builtin_amdgcn_mfma_f32_16x16x32_bf16(afr[1][ca], b, acc[1][fc], 0, 0, 0);
      }
      if (more) {
        *(u32x4*)&kbuf[cur ^ 1][sdst[0]] = pf[0];
        *(u32x4*)&kbuf[cur ^ 1][sdst[1]] = pf[1];
      }
      __syncthreads();
      cur ^= 1;
    }

    // ---- selection on approx distances ----
    float k2v[4]; bool cv[4];
#pragma unroll
    for (int fc = 0; fc < 4; ++fc) {
      int cl = t0l + wc * 64 + fc * 16 + (lane & 15);
      cv[fc] = (cl < SLICE_LEN);
      k2v[fc] = cv[fc] ? k2g[m0 + cl] : 0.f;
    }
    u32 pend = 0;
#pragma unroll
    for (int fr = 0; fr < 2; ++fr)
#pragma unroll
      for (int fc = 0; fc < 4; ++fc)
        if (cv[fc]) pend |= 15u << ((((fr << 2) | fc) << 2));

    for (;;) {
      if (tid == 0) ovf = 0;
      __syncthreads();
      if (pend) {
#pragma unroll
        for (int fr = 0; fr < 2; ++fr) {
#pragma unroll
          for (int fc = 0; fc < 4; ++fc) {
#pragma unroll
            for (int rg = 0; rg < 4; ++rg) {
              u32 bit = 1u << ((((fr << 2) | fc) << 2) | rg);
              if (pend & bit) {
                int lrow = wr * 32 + fr * 16 + ((lane >> 4) << 2) + rg;
                int cl = t0l + wc * 64 + fc * 16 + (lane & 15);
                float dd = q2s[lrow] + k2v[fc] - 2.0f * acc[fr][fc][rg];
                u32 ck = (__float_as_uint(dd) & 0xFFFFE000u) | (u32)cl;
                if (ck < thresh[lrow]) {
                  int pos = atomicAdd(&cnt[lrow], 1);
                  if (pos < CAP) {
                    lbuf[(((size_t)(rb + lrow)) * NSLICE + slice) * CAP + pos] = ck;
                    pend &= ~bit;
                  } else ovf = 1;     // benign race
                } else pend &= ~bit;
              }
            }
          }
        }
      }
      __syncthreads();
      if (!ovf) break;
      __threadfence_block();
      compact_block(false, rb, slice, tid, sortbuf, thresh, cnt, lbuf);
      __syncthreads();
    }

#pragma unroll
    for (int fr = 0; fr < 2; ++fr)
#pragma unroll
      for (int fc = 0; fc < 4; ++fc)
        acc[fr][fc] = (f32x4){0.f, 0.f, 0.f, 0.f};
  }

  __threadfence_block();
  compact_block(true, rb, slice, tid, sortbuf, thresh, cnt, lbuf);
}

// ---------------- K4: merge 8x50 -> approx top-64 -> exact fp32 rerank -> output ------
__global__ __launch_bounds__(256) void k4_rerank(
    const u32* __restrict__ lbuf, const float* __restrict__ qrow,
    const float* __restrict__ q2g, const float* __restrict__ k2g,
    const float* __restrict__ keys, const float* __restrict__ memv,
    const float* __restrict__ net, float* __restrict__ out)
{
  __shared__ u64 sb[512];
  __shared__ float qs[128];
  __shared__ float part[4][RR];
  __shared__ u64 cand[RR];
  int b = blockIdx.x, t = threadIdx.x;
  if (t < 128) qs[t] = qrow[(size_t)b * D_ + t];
#pragma unroll
  for (int h = 0; h < 2; ++h) {
    int e = t + (h << 8);
    u64 v = ~0ull;
    if (e < NSLICE * KNN) {
      int s = e / KNN, j = e - s * KNN;
      u32 k32 = lbuf[((size_t)b * NSLICE + s) * CAP + j];
      v = ((u64)(k32 & 0xFFFFE000u) << 32) | (u32)(s * SLICE_LEN + (k32 & 0x1FFFu));
    }
    sb[e] = v;
  }
  __syncthreads();
  for (int k = 2; k <= 512; k <<= 1)
    for (int j = k >> 1; j > 0; j >>= 1) {
#pragma unroll
      for (int h = 0; h < 2; ++h) {
        int e = t + (h << 8);
        int p = e ^ j;
        if (p > e) {
          u64 x = sb[e], y = sb[p];
          bool up = ((e & k) == 0);
          if ((x > y) == up) { sb[e] = y; sb[p] = x; }
        }
      }
      __syncthreads();
    }

  // exact rerank of approx-top-RR
  int cid = t & 63, g = t >> 6;
  u32 gidx = (u32)sb[cid];
  const float* kp = keys + (size_t)gidx * D_ + g * 32;
  float dot = 0.f;
#pragma unroll
  for (int i = 0; i < 8; ++i) {
    float4 kv = *(const float4*)(kp + i * 4);
    float4 qv = *(const float4*)&qs[g * 32 + i * 4];
    dot = fmaf(kv.x, qv.x, dot); dot = fmaf(kv.y, qv.y, dot);
    dot = fmaf(kv.z, qv.z, dot); dot = fmaf(kv.w, qv.w, dot);
  }
  part[g][cid] = dot;
  __syncthreads();
  if (t < RR) {
    float dotf = part[0][t] + part[1][t] + part[2][t] + part[3][t];
    u32 gi = (u32)sb[t];
    float dd = q2g[b] + k2g[gi] - 2.0f * dotf;
    cand[t] = ((u64)__float_as_uint(dd) << 32) | gi;
  }
  __syncthreads();
  if (t < 64) {
    for (int k = 2; k <= 64; k <<= 1)
      for (int j = k >> 1; j > 0; j >>= 1) {
        u64 x = cand[t], y = cand[t ^ j];
        __builtin_amdgcn_wave_barrier();
        bool up = ((t & k) == 0);
        u64 mn = x < y ? x : y, mx = x < y ? y : x;
        cand[t] = ((t < (t ^ j)) == up) ? mn : mx;
        __builtin_amdgcn_wave_barrier();
      }
    u64 key = cand[t];
    float d = __uint_as_float((u32)(key >> 32));
    u32 idx = (u32)key;
    float w = 0.f, wv = 0.f;
    if (t < KNN) {
      float ww = 1.0f / (d + 1e-7f);
      w = ww;
      wv = ww * memv[idx];
    }
#pragma unroll
    for (int o = 1; o < 64; o <<= 1) {
      w += __shfl_xor(w, o);
      wv += __shfl_xor(wv, o);
    }
    if (t == 0) out[b] = 0.9f * (wv / w) + 0.1f * net[b];
  }
}

// ---------------- launch --------------------------------------------------------------
extern "C" void kernel_launch(void* const* d_in, const int* in_sizes, int n_in,
                              void* d_out, int out_size, void* d_ws, size_t ws_size,
                              hipStream_t stream)
{
  const float* states     = (const float*)d_in[0];
  const float* W1         = (const float*)d_in[1];
  const float* b1         = (const float*)d_in[2];
  const float* W2         = (const float*)d_in[3];
  const float* b2         = (const float*)d_in[4];
  const float* lng        = (const float*)d_in[5];
  const float* lnb        = (const float*)d_in[6];
  const float* mem_keys   = (const float*)d_in[7];
  const float* mem_values = (const float*)d_in[8];
  const float* V1         = (const float*)d_in[9];
  const float* c1         = (const float*)d_in[10];
  const float* V2         = (const float*)d_in[11];
  const float* c2         = (const float*)d_in[12];
  const float* V3         = (const float*)d_in[13];
  const float* c3         = (const float*)d_in[14];
  float* out = (float*)d_out;

  char* ws = (char*)d_ws;
  u32*   qext = (u32*)(ws + 0);             // 2 MB  [B][128 u32]
  float* qrow = (float*)(ws + 2097152);     // 2 MB  [B][128] f32
  float* q2   = (float*)(ws + 4194304);     // 16 KB
  float* net  = (float*)(ws + 4210688);     // 16 KB
  float* k2g  = (float*)(ws + 4227072);     // 200 KB (to 4431872)
  u32*  keyext = (u32*)(ws + 4456448);      // 25.6 MB [M][128 u32] (to 30056448)
  u32*  lbuf  = (u32*)(ws + 30056448);      // 11.53 MB (to 41590784)
  // h / v1 overlay the keyext region: dead before k5 writes it
  float* h    = (float*)(ws + 4456448);             // 4 MB
  float* v1   = (float*)(ws + 4456448 + 4194304);   // 4 MB

  k1_gemm<<<dim3(H_ / 64, B_ / 64, 2), 256, 0, stream>>>(states, W1, b1, V1, c1, h, v1);
  k2_fused<<<dim3(B_ / 32), 256, 0, stream>>>(0, h, W2, b2, lng, lnb, V3, c3, qext, qrow, q2, net);
  k2_fused<<<dim3(B_ / 32), 256, 0, stream>>>(1, v1, V2, c2, lng, lnb, V3, c3, qext, qrow, q2, net);
  k5_keyext<<<dim3((M_ + 63) / 64), 256, 0, stream>>>(mem_keys, keyext, k2g);
  k3_knn<<<dim3((B_ / 64) * NSLICE), 256, 0, stream>>>(qext, q2, keyext, k2g, lbuf);
  k4_rerank<<<dim3(B_), 256, 0, stream>>>(lbuf, qrow, q2, k2g, mem_keys, mem_values, net, out);
}

// Round 5
// 1003.315 us; speedup vs baseline: 3.1207x; 1.8229x over previous
//
#include <hip/hip_runtime.h>
#include <stdint.h>

#define B_   4096
#define S_   544
#define H_   256
#define D_   128
#define M_   50000
#define KNN  50
#define NSLICE 8
#define SL_REAL 6250
#define BKEY 128
#define NB   49                  // buffers per slice
#define SL_PAD (NB * BKEY)       // 6272
#define CAP  128
#define RR   64
#define IMG_U32 10240            // 5 chunks * 128 keys * 16 u32 = 40KB per block-image

typedef unsigned long long u64;
typedef unsigned int u32;
typedef __attribute__((ext_vector_type(8))) __bf16 bf16x8;
typedef __attribute__((ext_vector_type(8))) unsigned short u16x8;
typedef __attribute__((ext_vector_type(4))) float f32x4;
typedef __attribute__((ext_vector_type(4))) u32 u32x4;

__device__ __forceinline__ u32 bf16_rne(float x) {
  u32 u = __float_as_uint(x);
  return (u + 0x7FFFu + ((u >> 16) & 1u)) >> 16;
}

__device__ __forceinline__ void gl_lds16(const u32* g, u32* l) {
  __builtin_amdgcn_global_load_lds(
      (const __attribute__((address_space(1))) u32*)g,
      (__attribute__((address_space(3))) u32*)l, 16, 0, 0);
}

// ---------------- K1: h = relu(states@W1+b1) (z=0), v1 = relu(states@V1+c1) (z=1) ----
__global__ __launch_bounds__(256) void k1_gemm(
    const float* __restrict__ A,
    const float* __restrict__ W1, const float* __restrict__ b1,
    const float* __restrict__ V1, const float* __restrict__ c1,
    float* __restrict__ hout, float* __restrict__ v1out)
{
  const float* W    = (blockIdx.z == 0) ? W1 : V1;
  const float* bias = (blockIdx.z == 0) ? b1 : c1;
  float* out        = (blockIdx.z == 0) ? hout : v1out;

  __shared__ float as[16][68];
  __shared__ float bs[16][64];

  int tid = threadIdx.x;
  int tx = tid & 15, ty = tid >> 4;
  int rb = blockIdx.y * 64, cb = blockIdx.x * 64;

  float acc[4][4] = {};

  for (int k0 = 0; k0 < S_; k0 += 16) {
    {
      int r = tid >> 2, k4 = (tid & 3) << 2;
      float4 a = *(const float4*)&A[(size_t)(rb + r) * S_ + k0 + k4];
      as[k4 + 0][r] = a.x; as[k4 + 1][r] = a.y;
      as[k4 + 2][r] = a.z; as[k4 + 3][r] = a.w;
    }
    {
      int kk = tid >> 4, c4 = (tid & 15) << 2;
      *(float4*)&bs[kk][c4] = *(const float4*)&W[(size_t)(k0 + kk) * H_ + cb + c4];
    }
    __syncthreads();
#pragma unroll
    for (int kk = 0; kk < 16; ++kk) {
      float4 a4 = *(const float4*)&as[kk][ty << 2];
      float4 b4 = *(const float4*)&bs[kk][tx << 2];
      float av[4] = {a4.x, a4.y, a4.z, a4.w};
      float bv[4] = {b4.x, b4.y, b4.z, b4.w};
#pragma unroll
      for (int i = 0; i < 4; ++i)
#pragma unroll
        for (int j = 0; j < 4; ++j)
          acc[i][j] = fmaf(av[i], bv[j], acc[i][j]);
    }
    __syncthreads();
  }

#pragma unroll
  for (int i = 0; i < 4; ++i) {
    int r = rb + (ty << 2) + i;
#pragma unroll
    for (int j = 0; j < 4; ++j) {
      int c = cb + (tx << 2) + j;
      float v = acc[i][j] + bias[c];
      out[(size_t)r * H_ + c] = v > 0.0f ? v : 0.0f;
    }
  }
}

// ---------------- K2: mode 0: q = LN(h@W2+b2) -> qrow(f32), qext2(bf16 of -2q), q2
//                      mode 1: v2 = relu(v1@V2+c2); net = v2@V3 + c3 ------------------
__global__ __launch_bounds__(256) void k2_fused(
    int mode,
    const float* __restrict__ A,      // [B_][H_]
    const float* __restrict__ W,      // [H_][D_]
    const float* __restrict__ bias,   // [D_]
    const float* __restrict__ lng, const float* __restrict__ lnb,
    const float* __restrict__ V3, const float* __restrict__ c3,
    ushort* __restrict__ qext2, float* __restrict__ qrow,
    float* __restrict__ q2out, float* __restrict__ netout)
{
  __shared__ float as[32][36];
  __shared__ float bs[32][132];
  __shared__ float yt[32][132];
  __shared__ float v3s[128];

  int tid = threadIdx.x;
  int tx = tid & 31, ty = tid >> 5;
  int rb = blockIdx.x * 32;

  if (mode == 1 && tid < 128) v3s[tid] = V3[tid];

  float acc[4][4] = {};

  for (int k0 = 0; k0 < H_; k0 += 32) {
    {
      int r = tid >> 3, k4 = (tid & 7) << 2;
      float4 a = *(const float4*)&A[(size_t)(rb + r) * H_ + k0 + k4];
      as[k4 + 0][r] = a.x; as[k4 + 1][r] = a.y;
      as[k4 + 2][r] = a.z; as[k4 + 3][r] = a.w;
    }
    {
      int kk = tid >> 3, c16 = (tid & 7) << 4;
#pragma unroll
      for (int t = 0; t < 4; ++t)
        *(float4*)&bs[kk][c16 + (t << 2)] =
            *(const float4*)&W[(size_t)(k0 + kk) * D_ + c16 + (t << 2)];
    }
    __syncthreads();
#pragma unroll
    for (int kk = 0; kk < 32; ++kk) {
      float4 a4 = *(const float4*)&as[kk][ty << 2];
      float4 b4 = *(const float4*)&bs[kk][tx << 2];
      float av[4] = {a4.x, a4.y, a4.z, a4.w};
      float bv[4] = {b4.x, b4.y, b4.z, b4.w};
#pragma unroll
      for (int i = 0; i < 4; ++i)
#pragma unroll
        for (int j = 0; j < 4; ++j)
          acc[i][j] = fmaf(av[i], bv[j], acc[i][j]);
    }
    __syncthreads();
  }

#pragma unroll
  for (int i = 0; i < 4; ++i)
#pragma unroll
    for (int j = 0; j < 4; ++j) {
      int c = (tx << 2) + j;
      yt[(ty << 2) + i][c] = acc[i][j] + bias[c];
    }
  __syncthreads();

  int r8 = tid >> 3, j8 = tid & 7;
  int rg = rb + r8;
  if (mode == 0) {
    float s = 0.f;
#pragma unroll
    for (int t = 0; t < 16; ++t) s += yt[r8][(j8 << 4) + t];
    s += __shfl_xor(s, 1); s += __shfl_xor(s, 2); s += __shfl_xor(s, 4);
    float mu = s * (1.0f / 128.0f);
    float vs = 0.f;
#pragma unroll
    for (int t = 0; t < 16; ++t) {
      float d = yt[r8][(j8 << 4) + t] - mu;
      vs = fmaf(d, d, vs);
    }
    vs += __shfl_xor(vs, 1); vs += __shfl_xor(vs, 2); vs += __shfl_xor(vs, 4);
    float var = vs * (1.0f / 128.0f);
    float rstd = 1.0f / sqrtf(var + 1e-5f);
    float q2p = 0.f;
    ushort* qe = qext2 + (size_t)rg * 128;
#pragma unroll
    for (int t = 0; t < 16; ++t) {
      int c = (j8 << 4) + t;
      float qv = (yt[r8][c] - mu) * rstd * lng[c] + lnb[c];
      qrow[(size_t)rg * D_ + c] = qv;
      qe[c] = (ushort)bf16_rne(-2.0f * qv);
      q2p = fmaf(qv, qv, q2p);
    }
    q2p += __shfl_xor(q2p, 1); q2p += __shfl_xor(q2p, 2); q2p += __shfl_xor(q2p, 4);
    if (j8 == 0) q2out[rg] = q2p;
  } else {
    float s = 0.f;
#pragma unroll
    for (int t = 0; t < 16; ++t) {
      int c = (j8 << 4) + t;
      float v = yt[r8][c];
      v = v > 0.f ? v : 0.f;
      s = fmaf(v, v3s[c], s);
    }
    s += __shfl_xor(s, 1); s += __shfl_xor(s, 2); s += __shfl_xor(s, 4);
    if (j8 == 0) netout[rg] = s + c3[0];
  }
}

// ---------------- K5: build pre-swizzled key image + exact k2 norms -------------------
// image per (slice, block): [chunk 0..4][key 0..127][16 u32]; chunks 0-3 = bf16(k),
// chunk 4 = [k2_hi, k2_lo, 0...] (pads: chunks 0-3 zero, chunk4 word0 = NaN|NaN)
__global__ __launch_bounds__(256) void k5_keyimg(
    const float* __restrict__ keys, u32* __restrict__ keyimg,
    float* __restrict__ k2out)
{
  int tid = threadIdx.x;
  int p = blockIdx.x * 128 + (tid >> 1);   // padded key index
  int sub = tid & 1;
  int slice = p / SL_PAD;
  int within = p - slice * SL_PAD;
  int kb = within >> 7, kib = within & 127;
  u32* img = keyimg + (size_t)(slice * NB + kb) * IMG_U32;
  bool real = within < SL_REAL;

  u32 w[32];
  float ss = 0.f;
  if (real) {
    const float* kp = keys + (size_t)(slice * SL_REAL + within) * D_ + sub * 64;
#pragma unroll
    for (int i = 0; i < 16; ++i) {
      float4 x = *(const float4*)(kp + i * 4);
      ss = fmaf(x.x, x.x, fmaf(x.y, x.y, fmaf(x.z, x.z, fmaf(x.w, x.w, ss))));
      w[i * 2]     = bf16_rne(x.x) | (bf16_rne(x.y) << 16);
      w[i * 2 + 1] = bf16_rne(x.z) | (bf16_rne(x.w) << 16);
    }
  } else {
#pragma unroll
    for (int i = 0; i < 32; ++i) w[i] = 0;
  }
#pragma unroll
  for (int cc = 0; cc < 2; ++cc) {
    int c = sub * 2 + cc;
#pragma unroll
    for (int j = 0; j < 4; ++j) {
      u32x4 v = {w[cc*16 + j*4], w[cc*16 + j*4 + 1], w[cc*16 + j*4 + 2], w[cc*16 + j*4 + 3]};
      *(u32x4*)&img[c * 2048 + kib * 16 + j * 4] = v;
    }
  }
  float tot = ss + __shfl_xor(ss, 1);
  if (sub == 0) {
    u32 w0;
    if (real) {
      k2out[slice * SL_REAL + within] = tot;
      u32 h = bf16_rne(tot);
      float hf = __uint_as_float(h << 16);
      u32 lo = bf16_rne(tot - hf);
      w0 = h | (lo << 16);
    } else {
      w0 = 0x7FC07FC0u;   // NaN,NaN -> dd = NaN -> never selected
    }
    u32x4 v0 = {w0, 0, 0, 0};
    u32x4 z  = {0, 0, 0, 0};
    *(u32x4*)&img[4 * 2048 + kib * 16 + 0] = v0;
    *(u32x4*)&img[4 * 2048 + kib * 16 + 4] = z;
    *(u32x4*)&img[4 * 2048 + kib * 16 + 8] = z;
    *(u32x4*)&img[4 * 2048 + kib * 16 + 12] = z;
  }
}

// ---------------- K3 helpers ----------------------------------------------------------
__device__ __forceinline__ void sort128_wave(u32* sb, int lane) {
  for (int k = 2; k <= 128; k <<= 1)
    for (int j = k >> 1; j > 0; j >>= 1) {
#pragma unroll
      for (int half = 0; half < 2; ++half) {
        int e = lane + (half << 6);
        int pp = e ^ j;
        if (pp > e) {
          u32 x = sb[e], y = sb[pp];
          bool up = ((e & k) == 0);
          if ((x > y) == up) { sb[e] = y; sb[pp] = x; }
        }
      }
      __builtin_amdgcn_wave_barrier();
    }
}

// 8 waves x 16 rows
__device__ void compact_block(
    bool final_, int rb, int slice, int tid,
    u32 (*sortbuf)[128], float* threshL, int* cnt, u32* lbuf)
{
  int w = tid >> 6, lane = tid & 63;
  for (int rr = 0; rr < 16; ++rr) {
    int r = (w << 4) | rr;
    int c0 = cnt[r];
    if (!final_ && c0 <= CAP) continue;
    int valid = c0 < CAP ? c0 : CAP;
    u32* gb = &lbuf[(((size_t)(rb + r)) * NSLICE + slice) * CAP];
    u32 e0 = (lane < valid) ? gb[lane] : 0xFFFFFFFFu;
    u32 e1 = (lane + 64 < valid) ? gb[lane + 64] : 0xFFFFFFFFu;
    u32* sb = sortbuf[w];
    sb[lane] = e0; sb[lane + 64] = e1;
    __builtin_amdgcn_wave_barrier();
    sort128_wave(sb, lane);
    __builtin_amdgcn_wave_barrier();
    if (lane < KNN) gb[lane] = sb[lane];
    if (lane == 0) { cnt[r] = KNN; threshL[r] = __uint_as_float(sb[KNN - 1]); }
    __builtin_amdgcn_wave_barrier();
  }
}

// ---------------- K3: K=160 bf16 MFMA distance GEMM + approx top-50 -------------------
__global__ __launch_bounds__(512, 2) void k3_knn(
    const ushort* __restrict__ qext2,  // [B][128] bf16 of (-2q)
    const float* __restrict__ q2g,
    const u32* __restrict__ keyimg,    // pre-swizzled images
    u32* __restrict__ lbuf)
{
  __shared__ u32 kbuf[2][IMG_U32];     // 2 x 40KB
  __shared__ u32 sortbuf[8][128];
  __shared__ float threshL[128];
  __shared__ int cnt[128];
  __shared__ int ovf;

  int tid = threadIdx.x;
  int l = tid & 63, w = tid >> 6;
  int slice = blockIdx.x & 7;          // consecutive blocks -> different XCDs, slice-pinned
  int rb = (blockIdx.x >> 3) << 7;     // 128 q rows per block

  if (tid < 128) { threshL[tid] = __uint_as_float(0x7F800000u); cnt[tid] = 0; }
  if (tid == 0) ovf = 0;

  // ---- B-frags: q side, chunks 0..3 in registers for the whole kernel ----
  int l15 = l & 15, l4 = l >> 4;
  bf16x8 bfr[4][8];
#pragma unroll
  for (int c = 0; c < 4; ++c)
#pragma unroll
    for (int qf = 0; qf < 8; ++qf) {
      const ushort* qp = qext2 + (size_t)(rb + qf * 16 + l15) * 128 + c * 32 + l4 * 8;
      bfr[c][qf] = __builtin_bit_cast(bf16x8, *(const u32x4*)qp);
    }
  // chunk 4 B-frag: [1,1,0,...] for k-slice 0 lanes, zero otherwise
  bf16x8 bk2;
  {
    u16x8 v = {0, 0, 0, 0, 0, 0, 0, 0};
    if (l4 == 0) { v[0] = 0x3F80; v[1] = 0x3F80; }
    bk2 = __builtin_bit_cast(bf16x8, v);
  }
  float q2v[8];
#pragma unroll
  for (int qf = 0; qf < 8; ++qf) q2v[qf] = q2g[rb + qf * 16 + l15];

  const u32* imgbase = keyimg + (size_t)slice * NB * IMG_U32;

  // stage buffer b with block-image t (5 x global_load_lds_dwordx4 per wave)
  auto stage = [&](int b, int t) {
    const u32* src = imgbase + (size_t)t * IMG_U32 + w * 1280 + l * 4;
    u32* dst = &kbuf[b][w * 1280];
#pragma unroll
    for (int i = 0; i < 5; ++i)
      gl_lds16(src + i * 256, dst + i * 256);
  };

  stage(0, 0);
  __syncthreads();

  int cur = 0;
  for (int t = 0; t < NB; ++t) {
    if (t + 1 < NB) stage(cur ^ 1, t + 1);   // issue-early; drained by selection barriers

    f32x4 acc[8];
#pragma unroll
    for (int qf = 0; qf < 8; ++qf) acc[qf] = (f32x4){0.f, 0.f, 0.f, 0.f};

#pragma unroll
    for (int c = 0; c < 5; ++c) {
      bf16x8 a = __builtin_bit_cast(bf16x8,
          *(const u32x4*)&kbuf[cur][c * 2048 + (w * 16 + l15) * 16 + l4 * 4]);
#pragma unroll
      for (int qf = 0; qf < 8; ++qf)
        acc[qf] = __builtin_amdgcn_mfma_f32_16x16x32_bf16(
            a, (c < 4) ? bfr[c][qf] : bk2, acc[qf], 0, 0, 0);
    }

    // ---- selection: acc = -2*dot + k2 ; dd = q2 + acc ----
    float thF[8];
#pragma unroll
    for (int qf = 0; qf < 8; ++qf) thF[qf] = threshL[qf * 16 + l15];

    u32 pend = 0xFFFFFFFFu;
    for (;;) {
      if (tid == 0) ovf = 0;
      __syncthreads();
      if (pend) {
#pragma unroll
        for (int qf = 0; qf < 8; ++qf) {
          int row = qf * 16 + l15;
#pragma unroll
          for (int r = 0; r < 4; ++r) {
            u32 bit = 1u << ((qf << 2) | r);
            if (pend & bit) {
              float dd = q2v[qf] + acc[qf][r];
              if (dd < thF[qf]) {
                int pos = atomicAdd(&cnt[row], 1);
                if (pos < CAP) {
                  int kl = t * 128 + w * 16 + (l4 << 2) + r;
                  lbuf[(((size_t)(rb + row)) * NSLICE + slice) * CAP + pos] =
                      (__float_as_uint(dd) & 0xFFFFE000u) | (u32)kl;
                  pend &= ~bit;
                } else ovf = 1;     // benign race
              } else pend &= ~bit;
            }
          }
        }
      }
      __syncthreads();
      if (!ovf) break;
      compact_block(false, rb, slice, tid, sortbuf, threshL, cnt, lbuf);
      __syncthreads();
#pragma unroll
      for (int qf = 0; qf < 8; ++qf) thF[qf] = threshL[qf * 16 + l15];
    }
    cur ^= 1;
  }

  compact_block(true, rb, slice, tid, sortbuf, threshL, cnt, lbuf);
}

// ---------------- K4: merge 8x50 -> approx top-64 -> exact fp32 rerank -> output ------
__global__ __launch_bounds__(256) void k4_rerank(
    const u32* __restrict__ lbuf, const float* __restrict__ qrow,
    const float* __restrict__ q2g, const float* __restrict__ k2g,
    const float* __restrict__ keys, const float* __restrict__ memv,
    const float* __restrict__ net, float* __restrict__ out)
{
  __shared__ u64 sb[512];
  __shared__ float qs[128];
  __shared__ float part[4][RR];
  __shared__ u64 cand[RR];
  int b = blockIdx.x, t = threadIdx.x;
  if (t < 128) qs[t] = qrow[(size_t)b * D_ + t];
#pragma unroll
  for (int h = 0; h < 2; ++h) {
    int e = t + (h << 8);
    u64 v = ~0ull;
    if (e < NSLICE * KNN) {
      int s = e / KNN, j = e - s * KNN;
      u32 k32 = lbuf[((size_t)b * NSLICE + s) * CAP + j];
      v = ((u64)(k32 & 0xFFFFE000u) << 32) | (u32)(s * SL_REAL + (k32 & 0x1FFFu));
    }
    sb[e] = v;
  }
  __syncthreads();
  for (int k = 2; k <= 512; k <<= 1)
    for (int j = k >> 1; j > 0; j >>= 1) {
#pragma unroll
      for (int h = 0; h < 2; ++h) {
        int e = t + (h << 8);
        int p = e ^ j;
        if (p > e) {
          u64 x = sb[e], y = sb[p];
          bool up = ((e & k) == 0);
          if ((x > y) == up) { sb[e] = y; sb[p] = x; }
        }
      }
      __syncthreads();
    }

  // exact rerank of approx-top-RR
  int cid = t & 63, g = t >> 6;
  u32 gidx = (u32)sb[cid];
  const float* kp = keys + (size_t)gidx * D_ + g * 32;
  float dot = 0.f;
#pragma unroll
  for (int i = 0; i < 8; ++i) {
    float4 kv = *(const float4*)(kp + i * 4);
    float4 qv = *(const float4*)&qs[g * 32 + i * 4];
    dot = fmaf(kv.x, qv.x, dot); dot = fmaf(kv.y, qv.y, dot);
    dot = fmaf(kv.z, qv.z, dot); dot = fmaf(kv.w, qv.w, dot);
  }
  part[g][cid] = dot;
  __syncthreads();
  if (t < RR) {
    float dotf = part[0][t] + part[1][t] + part[2][t] + part[3][t];
    u32 gi = (u32)sb[t];
    float dd = q2g[b] + k2g[gi] - 2.0f * dotf;
    cand[t] = ((u64)__float_as_uint(dd) << 32) | gi;
  }
  __syncthreads();
  if (t < 64) {
    for (int k = 2; k <= 64; k <<= 1)
      for (int j = k >> 1; j > 0; j >>= 1) {
        u64 x = cand[t], y = cand[t ^ j];
        __builtin_amdgcn_wave_barrier();
        bool up = ((t & k) == 0);
        u64 mn = x < y ? x : y, mx = x < y ? y : x;
        cand[t] = ((t < (t ^ j)) == up) ? mn : mx;
        __builtin_amdgcn_wave_barrier();
      }
    u64 key = cand[t];
    float d = __uint_as_float((u32)(key >> 32));
    u32 idx = (u32)key;
    float w = 0.f, wv = 0.f;
    if (t < KNN) {
      float ww = 1.0f / (d + 1e-7f);
      w = ww;
      wv = ww * memv[idx];
    }
#pragma unroll
    for (int o = 1; o < 64; o <<= 1) {
      w += __shfl_xor(w, o);
      wv += __shfl_xor(wv, o);
    }
    if (t == 0) out[b] = 0.9f * (wv / w) + 0.1f * net[b];
  }
}

// ---------------- launch --------------------------------------------------------------
extern "C" void kernel_launch(void* const* d_in, const int* in_sizes, int n_in,
                              void* d_out, int out_size, void* d_ws, size_t ws_size,
                              hipStream_t stream)
{
  const float* states     = (const float*)d_in[0];
  const float* W1         = (const float*)d_in[1];
  const float* b1         = (const float*)d_in[2];
  const float* W2         = (const float*)d_in[3];
  const float* b2         = (const float*)d_in[4];
  const float* lng        = (const float*)d_in[5];
  const float* lnb        = (const float*)d_in[6];
  const float* mem_keys   = (const float*)d_in[7];
  const float* mem_values = (const float*)d_in[8];
  const float* V1         = (const float*)d_in[9];
  const float* c1         = (const float*)d_in[10];
  const float* V2         = (const float*)d_in[11];
  const float* c2         = (const float*)d_in[12];
  const float* V3         = (const float*)d_in[13];
  const float* c3         = (const float*)d_in[14];
  float* out = (float*)d_out;

  char* ws = (char*)d_ws;
  ushort* qext2 = (ushort*)(ws + 0);          // 1 MB   [B][128] bf16(-2q)
  float*  qrow  = (float*)(ws + 1048576);     // 2 MB   [B][128] f32
  float*  q2    = (float*)(ws + 3145728);     // 16 KB
  float*  net   = (float*)(ws + 3162112);     // 16 KB
  float*  k2g   = (float*)(ws + 3178496);     // 200 KB (ends 3383296)
  u32*  keyimg  = (u32*)(ws + 3383296);       // 16.06 MB (ends 19,439,616)
  u32*  lbuf    = (u32*)(ws + 19439616);      // 16.78 MB (ends 36,216,832)
  // h / v1 overlay keyimg region: dead before k5 writes it
  float* h  = (float*)(ws + 3383296);             // 4 MB
  float* v1 = (float*)(ws + 3383296 + 4194304);   // 4 MB

  k1_gemm<<<dim3(H_ / 64, B_ / 64, 2), 256, 0, stream>>>(states, W1, b1, V1, c1, h, v1);
  k2_fused<<<dim3(B_ / 32), 256, 0, stream>>>(0, h, W2, b2, lng, lnb, V3, c3, qext2, qrow, q2, net);
  k2_fused<<<dim3(B_ / 32), 256, 0, stream>>>(1, v1, V2, c2, lng, lnb, V3, c3, qext2, qrow, q2, net);
  k5_keyimg<<<dim3(NSLICE * SL_PAD / 128), 256, 0, stream>>>(mem_keys, keyimg, k2g);
  k3_knn<<<dim3((B_ / 128) * NSLICE), 512, 0, stream>>>(qext2, q2, keyimg, lbuf);
  k4_rerank<<<dim3(B_), 256, 0, stream>>>(lbuf, qrow, q2, k2g, mem_keys, mem_values, net, out);
}

// Round 6
// 809.793 us; speedup vs baseline: 3.8665x; 1.2390x over previous
//
#include <hip/hip_runtime.h>
#include <stdint.h>

#define B_   4096
#define S_   544
#define H_   256
#define D_   128
#define M_   50000
#define KNN  50
#define NSLICE 8
#define SL_REAL 6250
#define BKEY 64
#define NB   98                  // 64-key tiles per slice
#define SL_PAD (NB * BKEY)       // 6272
#define CAP  128
#define RR   64
#define IMG_U32 5120             // 5 chunks * 4 kslices * 64 keys * 4 u32 = 20KB

typedef unsigned long long u64;
typedef unsigned int u32;
typedef __attribute__((ext_vector_type(8))) __bf16 bf16x8;
typedef __attribute__((ext_vector_type(8))) unsigned short u16x8;
typedef __attribute__((ext_vector_type(4))) float f32x4;
typedef __attribute__((ext_vector_type(4))) u32 u32x4;

__device__ __forceinline__ u32 bf16_rne(float x) {
  u32 u = __float_as_uint(x);
  return (u + 0x7FFFu + ((u >> 16) & 1u)) >> 16;
}

__device__ __forceinline__ void gl_lds16(const u32* g, u32* l) {
  __builtin_amdgcn_global_load_lds(
      (const __attribute__((address_space(1))) u32*)g,
      (__attribute__((address_space(3))) u32*)l, 16, 0, 0);
}

// ---------------- K1: h = relu(states@W1+b1) (z=0), v1 = relu(states@V1+c1) (z=1) ----
__global__ __launch_bounds__(256) void k1_gemm(
    const float* __restrict__ A,
    const float* __restrict__ W1, const float* __restrict__ b1,
    const float* __restrict__ V1, const float* __restrict__ c1,
    float* __restrict__ hout, float* __restrict__ v1out)
{
  const float* W    = (blockIdx.z == 0) ? W1 : V1;
  const float* bias = (blockIdx.z == 0) ? b1 : c1;
  float* out        = (blockIdx.z == 0) ? hout : v1out;

  __shared__ float as[16][68];
  __shared__ float bs[16][64];

  int tid = threadIdx.x;
  int tx = tid & 15, ty = tid >> 4;
  int rb = blockIdx.y * 64, cb = blockIdx.x * 64;

  float acc[4][4] = {};

  for (int k0 = 0; k0 < S_; k0 += 16) {
    {
      int r = tid >> 2, k4 = (tid & 3) << 2;
      float4 a = *(const float4*)&A[(size_t)(rb + r) * S_ + k0 + k4];
      as[k4 + 0][r] = a.x; as[k4 + 1][r] = a.y;
      as[k4 + 2][r] = a.z; as[k4 + 3][r] = a.w;
    }
    {
      int kk = tid >> 4, c4 = (tid & 15) << 2;
      *(float4*)&bs[kk][c4] = *(const float4*)&W[(size_t)(k0 + kk) * H_ + cb + c4];
    }
    __syncthreads();
#pragma unroll
    for (int kk = 0; kk < 16; ++kk) {
      float4 a4 = *(const float4*)&as[kk][ty << 2];
      float4 b4 = *(const float4*)&bs[kk][tx << 2];
      float av[4] = {a4.x, a4.y, a4.z, a4.w};
      float bv[4] = {b4.x, b4.y, b4.z, b4.w};
#pragma unroll
      for (int i = 0; i < 4; ++i)
#pragma unroll
        for (int j = 0; j < 4; ++j)
          acc[i][j] = fmaf(av[i], bv[j], acc[i][j]);
    }
    __syncthreads();
  }

#pragma unroll
  for (int i = 0; i < 4; ++i) {
    int r = rb + (ty << 2) + i;
#pragma unroll
    for (int j = 0; j < 4; ++j) {
      int c = cb + (tx << 2) + j;
      float v = acc[i][j] + bias[c];
      out[(size_t)r * H_ + c] = v > 0.0f ? v : 0.0f;
    }
  }
}

// ---------------- K2: mode 0: q = LN(h@W2+b2) -> qrow(f32), qext2(bf16 of -2q), q2
//                      mode 1: v2 = relu(v1@V2+c2); net = v2@V3 + c3 ------------------
__global__ __launch_bounds__(256) void k2_fused(
    int mode,
    const float* __restrict__ A,      // [B_][H_]
    const float* __restrict__ W,      // [H_][D_]
    const float* __restrict__ bias,   // [D_]
    const float* __restrict__ lng, const float* __restrict__ lnb,
    const float* __restrict__ V3, const float* __restrict__ c3,
    ushort* __restrict__ qext2, float* __restrict__ qrow,
    float* __restrict__ q2out, float* __restrict__ netout)
{
  __shared__ float as[32][36];
  __shared__ float bs[32][132];
  __shared__ float yt[32][132];
  __shared__ float v3s[128];

  int tid = threadIdx.x;
  int tx = tid & 31, ty = tid >> 5;
  int rb = blockIdx.x * 32;

  if (mode == 1 && tid < 128) v3s[tid] = V3[tid];

  float acc[4][4] = {};

  for (int k0 = 0; k0 < H_; k0 += 32) {
    {
      int r = tid >> 3, k4 = (tid & 7) << 2;
      float4 a = *(const float4*)&A[(size_t)(rb + r) * H_ + k0 + k4];
      as[k4 + 0][r] = a.x; as[k4 + 1][r] = a.y;
      as[k4 + 2][r] = a.z; as[k4 + 3][r] = a.w;
    }
    {
      int kk = tid >> 3, c16 = (tid & 7) << 4;
#pragma unroll
      for (int t = 0; t < 4; ++t)
        *(float4*)&bs[kk][c16 + (t << 2)] =
            *(const float4*)&W[(size_t)(k0 + kk) * D_ + c16 + (t << 2)];
    }
    __syncthreads();
#pragma unroll
    for (int kk = 0; kk < 32; ++kk) {
      float4 a4 = *(const float4*)&as[kk][ty << 2];
      float4 b4 = *(const float4*)&bs[kk][tx << 2];
      float av[4] = {a4.x, a4.y, a4.z, a4.w};
      float bv[4] = {b4.x, b4.y, b4.z, b4.w};
#pragma unroll
      for (int i = 0; i < 4; ++i)
#pragma unroll
        for (int j = 0; j < 4; ++j)
          acc[i][j] = fmaf(av[i], bv[j], acc[i][j]);
    }
    __syncthreads();
  }

#pragma unroll
  for (int i = 0; i < 4; ++i)
#pragma unroll
    for (int j = 0; j < 4; ++j) {
      int c = (tx << 2) + j;
      yt[(ty << 2) + i][c] = acc[i][j] + bias[c];
    }
  __syncthreads();

  int r8 = tid >> 3, j8 = tid & 7;
  int rg = rb + r8;
  if (mode == 0) {
    float s = 0.f;
#pragma unroll
    for (int t = 0; t < 16; ++t) s += yt[r8][(j8 << 4) + t];
    s += __shfl_xor(s, 1); s += __shfl_xor(s, 2); s += __shfl_xor(s, 4);
    float mu = s * (1.0f / 128.0f);
    float vs = 0.f;
#pragma unroll
    for (int t = 0; t < 16; ++t) {
      float d = yt[r8][(j8 << 4) + t] - mu;
      vs = fmaf(d, d, vs);
    }
    vs += __shfl_xor(vs, 1); vs += __shfl_xor(vs, 2); vs += __shfl_xor(vs, 4);
    float var = vs * (1.0f / 128.0f);
    float rstd = 1.0f / sqrtf(var + 1e-5f);
    float q2p = 0.f;
    ushort* qe = qext2 + (size_t)rg * 128;
#pragma unroll
    for (int t = 0; t < 16; ++t) {
      int c = (j8 << 4) + t;
      float qv = (yt[r8][c] - mu) * rstd * lng[c] + lnb[c];
      qrow[(size_t)rg * D_ + c] = qv;
      qe[c] = (ushort)bf16_rne(-2.0f * qv);
      q2p = fmaf(qv, qv, q2p);
    }
    q2p += __shfl_xor(q2p, 1); q2p += __shfl_xor(q2p, 2); q2p += __shfl_xor(q2p, 4);
    if (j8 == 0) q2out[rg] = q2p;
  } else {
    float s = 0.f;
#pragma unroll
    for (int t = 0; t < 16; ++t) {
      int c = (j8 << 4) + t;
      float v = yt[r8][c];
      v = v > 0.f ? v : 0.f;
      s = fmaf(v, v3s[c], s);
    }
    s += __shfl_xor(s, 1); s += __shfl_xor(s, 2); s += __shfl_xor(s, 4);
    if (j8 == 0) netout[rg] = s + c3[0];
  }
}

// ---------------- K5: build kslice-major key image + exact k2 norms -------------------
// image per (slice, 64-key tile): [chunk c<5][kslice j<4][key<64][4 u32]
// chunk<4: bf16 dims (c*32+j*8 .. +7); chunk4 j=0: word0 = k2hi|k2lo<<16 (pad: NaN|NaN)
__global__ __launch_bounds__(256) void k5_keyimg(
    const float* __restrict__ keys, u32* __restrict__ keyimg,
    float* __restrict__ k2out)
{
  int tid = threadIdx.x;
  int p = blockIdx.x * 128 + (tid >> 1);   // padded key index
  int sub = tid & 1;
  int slice = p / SL_PAD;
  int within = p - slice * SL_PAD;
  int kb = within >> 6, kib = within & 63;
  u32* img = keyimg + (size_t)(slice * NB + kb) * IMG_U32;
  bool real = within < SL_REAL;

  u32 w[32];
  float ss = 0.f;
  if (real) {
    const float* kp = keys + (size_t)(slice * SL_REAL + within) * D_ + sub * 64;
#pragma unroll
    for (int i = 0; i < 16; ++i) {
      float4 x = *(const float4*)(kp + i * 4);
      ss = fmaf(x.x, x.x, fmaf(x.y, x.y, fmaf(x.z, x.z, fmaf(x.w, x.w, ss))));
      w[i * 2]     = bf16_rne(x.x) | (bf16_rne(x.y) << 16);
      w[i * 2 + 1] = bf16_rne(x.z) | (bf16_rne(x.w) << 16);
    }
  } else {
#pragma unroll
    for (int i = 0; i < 32; ++i) w[i] = 0;
  }
#pragma unroll
  for (int cc = 0; cc < 2; ++cc) {
    int c = sub * 2 + cc;
#pragma unroll
    for (int j = 0; j < 4; ++j) {
      u32x4 v = {w[cc*16 + j*4], w[cc*16 + j*4 + 1], w[cc*16 + j*4 + 2], w[cc*16 + j*4 + 3]};
      *(u32x4*)&img[c * 1024 + j * 256 + kib * 4] = v;
    }
  }
  float tot = ss + __shfl_xor(ss, 1);
  if (sub == 0) {
    u32 w0;
    if (real) {
      k2out[slice * SL_REAL + within] = tot;
      u32 h = bf16_rne(tot);
      float hf = __uint_as_float(h << 16);
      u32 lo = bf16_rne(tot - hf);
      w0 = h | (lo << 16);
    } else {
      w0 = 0x7FC07FC0u;   // NaN,NaN -> dd = NaN -> never selected
    }
    u32x4 v0 = {w0, 0, 0, 0};
    u32x4 z  = {0, 0, 0, 0};
    *(u32x4*)&img[4 * 1024 + 0 * 256 + kib * 4] = v0;
    *(u32x4*)&img[4 * 1024 + 1 * 256 + kib * 4] = z;
    *(u32x4*)&img[4 * 1024 + 2 * 256 + kib * 4] = z;
    *(u32x4*)&img[4 * 1024 + 3 * 256 + kib * 4] = z;
  }
}

// ---------------- K3 helpers ----------------------------------------------------------
__device__ __forceinline__ void sort128_wave(u32* sb, int lane) {
  for (int k = 2; k <= 128; k <<= 1)
    for (int j = k >> 1; j > 0; j >>= 1) {
#pragma unroll
      for (int half = 0; half < 2; ++half) {
        int e = lane + (half << 6);
        int pp = e ^ j;
        if (pp > e) {
          u32 x = sb[e], y = sb[pp];
          bool up = ((e & k) == 0);
          if ((x > y) == up) { sb[e] = y; sb[pp] = x; }
        }
      }
      __builtin_amdgcn_wave_barrier();
    }
}

// 8 waves x 8 rows
__device__ void compact_block(
    bool final_, int rb, int slice, int tid,
    u32 (*sortbuf)[128], float* threshL, int* cnt, u32* lbuf)
{
  int w = tid >> 6, lane = tid & 63;
  for (int rr = 0; rr < 8; ++rr) {
    int r = (w << 3) | rr;
    int c0 = cnt[r];
    if (!final_ && c0 <= CAP) continue;
    int valid = c0 < CAP ? c0 : CAP;
    u32* gb = &lbuf[(((size_t)(rb + r)) * NSLICE + slice) * CAP];
    u32 e0 = (lane < valid) ? gb[lane] : 0xFFFFFFFFu;
    u32 e1 = (lane + 64 < valid) ? gb[lane + 64] : 0xFFFFFFFFu;
    u32* sb = sortbuf[w];
    sb[lane] = e0; sb[lane + 64] = e1;
    __builtin_amdgcn_wave_barrier();
    sort128_wave(sb, lane);
    __builtin_amdgcn_wave_barrier();
    if (lane < KNN) gb[lane] = sb[lane];
    if (lane == 0) { cnt[r] = KNN; threshL[r] = __uint_as_float(sb[KNN - 1]); }
    __builtin_amdgcn_wave_barrier();
  }
}

// ---------------- K3: K=160 bf16 MFMA distance GEMM + approx top-50 -------------------
__global__ __launch_bounds__(512, 4) void k3_knn(
    const ushort* __restrict__ qext2,  // [B][128] bf16 of (-2q)
    const float* __restrict__ q2g,
    const u32* __restrict__ keyimg,    // kslice-major images
    u32* __restrict__ lbuf)
{
  __shared__ u32 kbuf[2][IMG_U32];     // 2 x 20KB
  __shared__ u32 sortbuf[8][128];      // 4KB
  __shared__ float threshL[64];
  __shared__ int cnt[64];
  __shared__ int ovf[2];

  int tid = threadIdx.x;
  int l = tid & 63, w = tid >> 6;
  int l15 = l & 15, l4 = l >> 4;
  int wr = w & 3, wc = w >> 2;         // wr: key quarter, wc: row half
  int slice = blockIdx.x & 7;          // consecutive blocks -> different XCDs
  int rb = (blockIdx.x >> 3) << 6;     // 64 q rows per block

  if (tid < 64) { threshL[tid] = __uint_as_float(0x7F800000u); cnt[tid] = 0; }
  if (tid == 0) { ovf[0] = 0; ovf[1] = 0; }

  // ---- B-frags (q side) in registers for the whole kernel ----
  bf16x8 bfr[4][2];
#pragma unroll
  for (int c = 0; c < 4; ++c)
#pragma unroll
    for (int qf = 0; qf < 2; ++qf) {
      const ushort* qp = qext2 + (size_t)(rb + wc * 32 + qf * 16 + l15) * 128 + c * 32 + l4 * 8;
      bfr[c][qf] = __builtin_bit_cast(bf16x8, *(const u32x4*)qp);
    }
  bf16x8 bk2;
  {
    u16x8 v = {0, 0, 0, 0, 0, 0, 0, 0};
    if (l4 == 0) { v[0] = 0x3F80; v[1] = 0x3F80; }
    bk2 = __builtin_bit_cast(bf16x8, v);
  }
  float q2v[2];
#pragma unroll
  for (int qf = 0; qf < 2; ++qf) q2v[qf] = q2g[rb + wc * 32 + qf * 16 + l15];

  const u32* imgbase = keyimg + (size_t)slice * NB * IMG_U32;

  // stage buffer b with tile t: waves 0-4 issue 4 x global_load_lds_dwordx4 each
  auto stage = [&](int b, int t) {
    if (w < 5) {
      const u32* src = imgbase + (size_t)t * IMG_U32 + w * 1024 + l * 4;
      u32* dst = &kbuf[b][w * 1024];
#pragma unroll
      for (int i = 0; i < 4; ++i)
        gl_lds16(src + i * 256, dst + i * 256);
    }
  };

  stage(0, 0);
  __syncthreads();

  int cur = 0;
  for (int t = 0; t < NB; ++t) {
    if (t + 1 < NB) stage(cur ^ 1, t + 1);   // in flight across compute+selection

    f32x4 acc[2] = {};
#pragma unroll
    for (int c = 0; c < 5; ++c) {
      bf16x8 a = __builtin_bit_cast(bf16x8,
          *(const u32x4*)&kbuf[cur][c * 1024 + l4 * 256 + (wr * 16 + l15) * 4]);
      acc[0] = __builtin_amdgcn_mfma_f32_16x16x32_bf16(a, (c < 4) ? bfr[c][0] : bk2, acc[0], 0, 0, 0);
      acc[1] = __builtin_amdgcn_mfma_f32_16x16x32_bf16(a, (c < 4) ? bfr[c][1] : bk2, acc[1], 0, 0, 0);
    }

    // ---- selection: dd = q2 + (-2*dot + k2) ----
    float ddv[2][4];
    float thF[2];
    thF[0] = threshL[wc * 32 + l15];
    thF[1] = threshL[wc * 32 + 16 + l15];
    u32 pend = 0;
#pragma unroll
    for (int qf = 0; qf < 2; ++qf)
#pragma unroll
      for (int r = 0; r < 4; ++r) {
        float dd = q2v[qf] + acc[qf][r];
        ddv[qf][r] = dd;
        if (dd < thF[qf]) pend |= 1u << ((qf << 2) | r);
      }

    if (pend) {
#pragma unroll
      for (int qf = 0; qf < 2; ++qf) {
        int row = wc * 32 + qf * 16 + l15;
#pragma unroll
        for (int r = 0; r < 4; ++r) {
          u32 bit = 1u << ((qf << 2) | r);
          if (pend & bit) {
            int pos = atomicAdd(&cnt[row], 1);
            if (pos < CAP) {
              int kl = t * BKEY + wr * 16 + (l4 << 2) + r;
              lbuf[(((size_t)(rb + row)) * NSLICE + slice) * CAP + pos] =
                  (__float_as_uint(ddv[qf][r]) & 0xFFFFE000u) | (u32)kl;
              pend &= ~bit;
            } else ovf[cur] = 1;    // benign race
          } else pend &= ~bit;      // no-op, keeps mask tidy
        }
      }
      // restore untested bits cleared above? none: bits not in pend were never set
    }

    __syncthreads();               // ONE barrier: stage drained, kbuf[cur] free, ovf visible

    if (ovf[cur]) {                // rare path
      do {
        compact_block(false, rb, slice, tid, sortbuf, threshL, cnt, lbuf);
        if (tid == 0) ovf[cur] = 0;
        __syncthreads();
        thF[0] = threshL[wc * 32 + l15];
        thF[1] = threshL[wc * 32 + 16 + l15];
        if (pend) {
#pragma unroll
          for (int qf = 0; qf < 2; ++qf) {
            int row = wc * 32 + qf * 16 + l15;
#pragma unroll
            for (int r = 0; r < 4; ++r) {
              u32 bit = 1u << ((qf << 2) | r);
              if (pend & bit) {
                if (ddv[qf][r] < thF[qf]) {
                  int pos = atomicAdd(&cnt[row], 1);
                  if (pos < CAP) {
                    int kl = t * BKEY + wr * 16 + (l4 << 2) + r;
                    lbuf[(((size_t)(rb + row)) * NSLICE + slice) * CAP + pos] =
                        (__float_as_uint(ddv[qf][r]) & 0xFFFFE000u) | (u32)kl;
                    pend &= ~bit;
                  } else ovf[cur] = 1;
                } else pend &= ~bit;
              }
            }
          }
        }
        __syncthreads();
      } while (ovf[cur]);
    }
    cur ^= 1;
  }

  compact_block(true, rb, slice, tid, sortbuf, threshL, cnt, lbuf);
}

// ---------------- K4: merge 8x50 -> approx top-64 -> exact fp32 rerank -> output ------
__global__ __launch_bounds__(256) void k4_rerank(
    const u32* __restrict__ lbuf, const float* __restrict__ qrow,
    const float* __restrict__ q2g, const float* __restrict__ k2g,
    const float* __restrict__ keys, const float* __restrict__ memv,
    const float* __restrict__ net, float* __restrict__ out)
{
  __shared__ u64 sb[512];
  __shared__ float qs[128];
  __shared__ float part[4][RR];
  __shared__ u64 cand[RR];
  int b = blockIdx.x, t = threadIdx.x;
  if (t < 128) qs[t] = qrow[(size_t)b * D_ + t];
#pragma unroll
  for (int h = 0; h < 2; ++h) {
    int e = t + (h << 8);
    u64 v = ~0ull;
    if (e < NSLICE * KNN) {
      int s = e / KNN, j = e - s * KNN;
      u32 k32 = lbuf[((size_t)b * NSLICE + s) * CAP + j];
      v = ((u64)(k32 & 0xFFFFE000u) << 32) | (u32)(s * SL_REAL + (k32 & 0x1FFFu));
    }
    sb[e] = v;
  }
  __syncthreads();
  for (int k = 2; k <= 512; k <<= 1)
    for (int j = k >> 1; j > 0; j >>= 1) {
#pragma unroll
      for (int h = 0; h < 2; ++h) {
        int e = t + (h << 8);
        int p = e ^ j;
        if (p > e) {
          u64 x = sb[e], y = sb[p];
          bool up = ((e & k) == 0);
          if ((x > y) == up) { sb[e] = y; sb[p] = x; }
        }
      }
      __syncthreads();
    }

  // exact rerank of approx-top-RR
  int cid = t & 63, g = t >> 6;
  u32 gidx = (u32)sb[cid];
  const float* kp = keys + (size_t)gidx * D_ + g * 32;
  float dot = 0.f;
#pragma unroll
  for (int i = 0; i < 8; ++i) {
    float4 kv = *(const float4*)(kp + i * 4);
    float4 qv = *(const float4*)&qs[g * 32 + i * 4];
    dot = fmaf(kv.x, qv.x, dot); dot = fmaf(kv.y, qv.y, dot);
    dot = fmaf(kv.z, qv.z, dot); dot = fmaf(kv.w, qv.w, dot);
  }
  part[g][cid] = dot;
  __syncthreads();
  if (t < RR) {
    float dotf = part[0][t] + part[1][t] + part[2][t] + part[3][t];
    u32 gi = (u32)sb[t];
    float dd = q2g[b] + k2g[gi] - 2.0f * dotf;
    cand[t] = ((u64)__float_as_uint(dd) << 32) | gi;
  }
  __syncthreads();
  if (t < 64) {
    for (int k = 2; k <= 64; k <<= 1)
      for (int j = k >> 1; j > 0; j >>= 1) {
        u64 x = cand[t], y = cand[t ^ j];
        __builtin_amdgcn_wave_barrier();
        bool up = ((t & k) == 0);
        u64 mn = x < y ? x : y, mx = x < y ? y : x;
        cand[t] = ((t < (t ^ j)) == up) ? mn : mx;
        __builtin_amdgcn_wave_barrier();
      }
    u64 key = cand[t];
    float d = __uint_as_float((u32)(key >> 32));
    u32 idx = (u32)key;
    float w = 0.f, wv = 0.f;
    if (t < KNN) {
      float ww = 1.0f / (d + 1e-7f);
      w = ww;
      wv = ww * memv[idx];
    }
#pragma unroll
    for (int o = 1; o < 64; o <<= 1) {
      w += __shfl_xor(w, o);
      wv += __shfl_xor(wv, o);
    }
    if (t == 0) out[b] = 0.9f * (wv / w) + 0.1f * net[b];
  }
}

// ---------------- launch --------------------------------------------------------------
extern "C" void kernel_launch(void* const* d_in, const int* in_sizes, int n_in,
                              void* d_out, int out_size, void* d_ws, size_t ws_size,
                              hipStream_t stream)
{
  const float* states     = (const float*)d_in[0];
  const float* W1         = (const float*)d_in[1];
  const float* b1         = (const float*)d_in[2];
  const float* W2         = (const float*)d_in[3];
  const float* b2         = (const float*)d_in[4];
  const float* lng        = (const float*)d_in[5];
  const float* lnb        = (const float*)d_in[6];
  const float* mem_keys   = (const float*)d_in[7];
  const float* mem_values = (const float*)d_in[8];
  const float* V1         = (const float*)d_in[9];
  const float* c1         = (const float*)d_in[10];
  const float* V2         = (const float*)d_in[11];
  const float* c2         = (const float*)d_in[12];
  const float* V3         = (const float*)d_in[13];
  const float* c3         = (const float*)d_in[14];
  float* out = (float*)d_out;

  char* ws = (char*)d_ws;
  ushort* qext2 = (ushort*)(ws + 0);          // 1 MB   [B][128] bf16(-2q)
  float*  qrow  = (float*)(ws + 1048576);     // 2 MB   [B][128] f32
  float*  q2    = (float*)(ws + 3145728);     // 16 KB
  float*  net   = (float*)(ws + 3162112);     // 16 KB
  float*  k2g   = (float*)(ws + 3178496);     // 200 KB (ends 3383296)
  u32*  keyimg  = (u32*)(ws + 3383296);       // 8*98*20KB = 16.06 MB (ends 19,439,616)
  u32*  lbuf    = (u32*)(ws + 19439616);      // 16.78 MB (ends 36,216,832)
  // h / v1 overlay keyimg region: dead before k5 writes it
  float* h  = (float*)(ws + 3383296);             // 4 MB
  float* v1 = (float*)(ws + 3383296 + 4194304);   // 4 MB

  k1_gemm<<<dim3(H_ / 64, B_ / 64, 2), 256, 0, stream>>>(states, W1, b1, V1, c1, h, v1);
  k2_fused<<<dim3(B_ / 32), 256, 0, stream>>>(0, h, W2, b2, lng, lnb, V3, c3, qext2, qrow, q2, net);
  k2_fused<<<dim3(B_ / 32), 256, 0, stream>>>(1, v1, V2, c2, lng, lnb, V3, c3, qext2, qrow, q2, net);
  k5_keyimg<<<dim3(NSLICE * SL_PAD / 128), 256, 0, stream>>>(mem_keys, keyimg, k2g);
  k3_knn<<<dim3((B_ / 64) * NSLICE), 512, 0, stream>>>(qext2, q2, keyimg, lbuf);
  k4_rerank<<<dim3(B_), 256, 0, stream>>>(lbuf, qrow, q2, k2g, mem_keys, mem_values, net, out);
}

// Round 7
// 808.039 us; speedup vs baseline: 3.8749x; 1.0022x over previous
//
#include <hip/hip_runtime.h>
#include <stdint.h>

#define B_   4096
#define S_   544
#define H_   256
#define D_   128
#define M_   50000
#define KNN  50
#define NSLICE 8
#define SL_REAL 6250
#define BKEY 64
#define NB   98                  // 64-key tiles per slice
#define SL_PAD (NB * BKEY)       // 6272
#define CAP  128
#define RR   64
#define IMG_U32 5120             // 5 chunks * 4 kslices * 64 keys * 4 u32 = 20KB

typedef unsigned long long u64;
typedef unsigned int u32;
typedef __attribute__((ext_vector_type(8))) __bf16 bf16x8;
typedef __attribute__((ext_vector_type(8))) unsigned short u16x8;
typedef __attribute__((ext_vector_type(4))) float f32x4;
typedef __attribute__((ext_vector_type(4))) u32 u32x4;

__device__ __forceinline__ u32 bf16_rne(float x) {
  u32 u = __float_as_uint(x);
  return (u + 0x7FFFu + ((u >> 16) & 1u)) >> 16;
}

__device__ __forceinline__ void gl_lds16(const u32* g, u32* l) {
  __builtin_amdgcn_global_load_lds(
      (const __attribute__((address_space(1))) u32*)g,
      (__attribute__((address_space(3))) u32*)l, 16, 0, 0);
}

// ---------------- K1: h = relu(states@W1+b1) (z=0), v1 = relu(states@V1+c1) (z=1) ----
__global__ __launch_bounds__(256) void k1_gemm(
    const float* __restrict__ A,
    const float* __restrict__ W1, const float* __restrict__ b1,
    const float* __restrict__ V1, const float* __restrict__ c1,
    float* __restrict__ hout, float* __restrict__ v1out)
{
  const float* W    = (blockIdx.z == 0) ? W1 : V1;
  const float* bias = (blockIdx.z == 0) ? b1 : c1;
  float* out        = (blockIdx.z == 0) ? hout : v1out;

  __shared__ float as[16][68];
  __shared__ float bs[16][64];

  int tid = threadIdx.x;
  int tx = tid & 15, ty = tid >> 4;
  int rb = blockIdx.y * 64, cb = blockIdx.x * 64;

  float acc[4][4] = {};

  for (int k0 = 0; k0 < S_; k0 += 16) {
    {
      int r = tid >> 2, k4 = (tid & 3) << 2;
      float4 a = *(const float4*)&A[(size_t)(rb + r) * S_ + k0 + k4];
      as[k4 + 0][r] = a.x; as[k4 + 1][r] = a.y;
      as[k4 + 2][r] = a.z; as[k4 + 3][r] = a.w;
    }
    {
      int kk = tid >> 4, c4 = (tid & 15) << 2;
      *(float4*)&bs[kk][c4] = *(const float4*)&W[(size_t)(k0 + kk) * H_ + cb + c4];
    }
    __syncthreads();
#pragma unroll
    for (int kk = 0; kk < 16; ++kk) {
      float4 a4 = *(const float4*)&as[kk][ty << 2];
      float4 b4 = *(const float4*)&bs[kk][tx << 2];
      float av[4] = {a4.x, a4.y, a4.z, a4.w};
      float bv[4] = {b4.x, b4.y, b4.z, b4.w};
#pragma unroll
      for (int i = 0; i < 4; ++i)
#pragma unroll
        for (int j = 0; j < 4; ++j)
          acc[i][j] = fmaf(av[i], bv[j], acc[i][j]);
    }
    __syncthreads();
  }

#pragma unroll
  for (int i = 0; i < 4; ++i) {
    int r = rb + (ty << 2) + i;
#pragma unroll
    for (int j = 0; j < 4; ++j) {
      int c = cb + (tx << 2) + j;
      float v = acc[i][j] + bias[c];
      out[(size_t)r * H_ + c] = v > 0.0f ? v : 0.0f;
    }
  }
}

// ---------------- K2: mode 0: q = LN(h@W2+b2) -> qrow(f32), qext2(bf16 of -2q), q2
//                      mode 1: v2 = relu(v1@V2+c2); net = v2@V3 + c3 ------------------
__global__ __launch_bounds__(256) void k2_fused(
    int mode,
    const float* __restrict__ A,      // [B_][H_]
    const float* __restrict__ W,      // [H_][D_]
    const float* __restrict__ bias,   // [D_]
    const float* __restrict__ lng, const float* __restrict__ lnb,
    const float* __restrict__ V3, const float* __restrict__ c3,
    ushort* __restrict__ qext2, float* __restrict__ qrow,
    float* __restrict__ q2out, float* __restrict__ netout)
{
  __shared__ float as[32][36];
  __shared__ float bs[32][132];
  __shared__ float yt[32][132];
  __shared__ float v3s[128];

  int tid = threadIdx.x;
  int tx = tid & 31, ty = tid >> 5;
  int rb = blockIdx.x * 32;

  if (mode == 1 && tid < 128) v3s[tid] = V3[tid];

  float acc[4][4] = {};

  for (int k0 = 0; k0 < H_; k0 += 32) {
    {
      int r = tid >> 3, k4 = (tid & 7) << 2;
      float4 a = *(const float4*)&A[(size_t)(rb + r) * H_ + k0 + k4];
      as[k4 + 0][r] = a.x; as[k4 + 1][r] = a.y;
      as[k4 + 2][r] = a.z; as[k4 + 3][r] = a.w;
    }
    {
      int kk = tid >> 3, c16 = (tid & 7) << 4;
#pragma unroll
      for (int t = 0; t < 4; ++t)
        *(float4*)&bs[kk][c16 + (t << 2)] =
            *(const float4*)&W[(size_t)(k0 + kk) * D_ + c16 + (t << 2)];
    }
    __syncthreads();
#pragma unroll
    for (int kk = 0; kk < 32; ++kk) {
      float4 a4 = *(const float4*)&as[kk][ty << 2];
      float4 b4 = *(const float4*)&bs[kk][tx << 2];
      float av[4] = {a4.x, a4.y, a4.z, a4.w};
      float bv[4] = {b4.x, b4.y, b4.z, b4.w};
#pragma unroll
      for (int i = 0; i < 4; ++i)
#pragma unroll
        for (int j = 0; j < 4; ++j)
          acc[i][j] = fmaf(av[i], bv[j], acc[i][j]);
    }
    __syncthreads();
  }

#pragma unroll
  for (int i = 0; i < 4; ++i)
#pragma unroll
    for (int j = 0; j < 4; ++j) {
      int c = (tx << 2) + j;
      yt[(ty << 2) + i][c] = acc[i][j] + bias[c];
    }
  __syncthreads();

  int r8 = tid >> 3, j8 = tid & 7;
  int rg = rb + r8;
  if (mode == 0) {
    float s = 0.f;
#pragma unroll
    for (int t = 0; t < 16; ++t) s += yt[r8][(j8 << 4) + t];
    s += __shfl_xor(s, 1); s += __shfl_xor(s, 2); s += __shfl_xor(s, 4);
    float mu = s * (1.0f / 128.0f);
    float vs = 0.f;
#pragma unroll
    for (int t = 0; t < 16; ++t) {
      float d = yt[r8][(j8 << 4) + t] - mu;
      vs = fmaf(d, d, vs);
    }
    vs += __shfl_xor(vs, 1); vs += __shfl_xor(vs, 2); vs += __shfl_xor(vs, 4);
    float var = vs * (1.0f / 128.0f);
    float rstd = 1.0f / sqrtf(var + 1e-5f);
    float q2p = 0.f;
    ushort* qe = qext2 + (size_t)rg * 128;
#pragma unroll
    for (int t = 0; t < 16; ++t) {
      int c = (j8 << 4) + t;
      float qv = (yt[r8][c] - mu) * rstd * lng[c] + lnb[c];
      qrow[(size_t)rg * D_ + c] = qv;
      qe[c] = (ushort)bf16_rne(-2.0f * qv);
      q2p = fmaf(qv, qv, q2p);
    }
    q2p += __shfl_xor(q2p, 1); q2p += __shfl_xor(q2p, 2); q2p += __shfl_xor(q2p, 4);
    if (j8 == 0) q2out[rg] = q2p;
  } else {
    float s = 0.f;
#pragma unroll
    for (int t = 0; t < 16; ++t) {
      int c = (j8 << 4) + t;
      float v = yt[r8][c];
      v = v > 0.f ? v : 0.f;
      s = fmaf(v, v3s[c], s);
    }
    s += __shfl_xor(s, 1); s += __shfl_xor(s, 2); s += __shfl_xor(s, 4);
    if (j8 == 0) netout[rg] = s + c3[0];
  }
}

// ---------------- K5: build kslice-major key image + exact k2 norms -------------------
// image per (slice, 64-key tile): [chunk c<5][kslice j<4][key<64][4 u32]
// chunk<4: bf16 dims (c*32+j*8 .. +7); chunk4 j=0: word0 = k2hi|k2lo<<16 (pad: NaN|NaN)
__global__ __launch_bounds__(256) void k5_keyimg(
    const float* __restrict__ keys, u32* __restrict__ keyimg,
    float* __restrict__ k2out)
{
  int tid = threadIdx.x;
  int p = blockIdx.x * 128 + (tid >> 1);   // padded key index
  int sub = tid & 1;
  int slice = p / SL_PAD;
  int within = p - slice * SL_PAD;
  int kb = within >> 6, kib = within & 63;
  u32* img = keyimg + (size_t)(slice * NB + kb) * IMG_U32;
  bool real = within < SL_REAL;

  u32 w[32];
  float ss = 0.f;
  if (real) {
    const float* kp = keys + (size_t)(slice * SL_REAL + within) * D_ + sub * 64;
#pragma unroll
    for (int i = 0; i < 16; ++i) {
      float4 x = *(const float4*)(kp + i * 4);
      ss = fmaf(x.x, x.x, fmaf(x.y, x.y, fmaf(x.z, x.z, fmaf(x.w, x.w, ss))));
      w[i * 2]     = bf16_rne(x.x) | (bf16_rne(x.y) << 16);
      w[i * 2 + 1] = bf16_rne(x.z) | (bf16_rne(x.w) << 16);
    }
  } else {
#pragma unroll
    for (int i = 0; i < 32; ++i) w[i] = 0;
  }
#pragma unroll
  for (int cc = 0; cc < 2; ++cc) {
    int c = sub * 2 + cc;
#pragma unroll
    for (int j = 0; j < 4; ++j) {
      u32x4 v = {w[cc*16 + j*4], w[cc*16 + j*4 + 1], w[cc*16 + j*4 + 2], w[cc*16 + j*4 + 3]};
      *(u32x4*)&img[c * 1024 + j * 256 + kib * 4] = v;
    }
  }
  float tot = ss + __shfl_xor(ss, 1);
  if (sub == 0) {
    u32 w0;
    if (real) {
      k2out[slice * SL_REAL + within] = tot;
      u32 h = bf16_rne(tot);
      float hf = __uint_as_float(h << 16);
      u32 lo = bf16_rne(tot - hf);
      w0 = h | (lo << 16);
    } else {
      w0 = 0x7FC07FC0u;   // NaN,NaN -> dd = NaN -> never selected
    }
    u32x4 v0 = {w0, 0, 0, 0};
    u32x4 z  = {0, 0, 0, 0};
    *(u32x4*)&img[4 * 1024 + 0 * 256 + kib * 4] = v0;
    *(u32x4*)&img[4 * 1024 + 1 * 256 + kib * 4] = z;
    *(u32x4*)&img[4 * 1024 + 2 * 256 + kib * 4] = z;
    *(u32x4*)&img[4 * 1024 + 3 * 256 + kib * 4] = z;
  }
}

// ---------------- K3 helpers ----------------------------------------------------------
__device__ __forceinline__ void sort128_wave(u32* sb, int lane) {
  for (int k = 2; k <= 128; k <<= 1)
    for (int j = k >> 1; j > 0; j >>= 1) {
#pragma unroll
      for (int half = 0; half < 2; ++half) {
        int e = lane + (half << 6);
        int pp = e ^ j;
        if (pp > e) {
          u32 x = sb[e], y = sb[pp];
          bool up = ((e & k) == 0);
          if ((x > y) == up) { sb[e] = y; sb[pp] = x; }
        }
      }
      __builtin_amdgcn_wave_barrier();
    }
}

// 8 waves x 8 rows
__device__ void compact_block(
    bool final_, int rb, int slice, int tid,
    u32 (*sortbuf)[128], float* threshL, int* cnt, u32* lbuf)
{
  int w = tid >> 6, lane = tid & 63;
  for (int rr = 0; rr < 8; ++rr) {
    int r = (w << 3) | rr;
    int c0 = cnt[r];
    if (!final_ && c0 <= CAP) continue;
    int valid = c0 < CAP ? c0 : CAP;
    u32* gb = &lbuf[(((size_t)(rb + r)) * NSLICE + slice) * CAP];
    u32 e0 = (lane < valid) ? gb[lane] : 0xFFFFFFFFu;
    u32 e1 = (lane + 64 < valid) ? gb[lane + 64] : 0xFFFFFFFFu;
    u32* sb = sortbuf[w];
    sb[lane] = e0; sb[lane + 64] = e1;
    __builtin_amdgcn_wave_barrier();
    sort128_wave(sb, lane);
    __builtin_amdgcn_wave_barrier();
    if (lane < KNN) gb[lane] = sb[lane];
    if (lane == 0) { cnt[r] = KNN; threshL[r] = __uint_as_float(sb[KNN - 1]); }
    __builtin_amdgcn_wave_barrier();
  }
}

// ---------------- K3: K=160 bf16 MFMA distance GEMM + approx top-50 -------------------
__global__ __launch_bounds__(512, 4) void k3_knn(
    const ushort* __restrict__ qext2,  // [B][128] bf16 of (-2q)
    const float* __restrict__ q2g,
    const u32* __restrict__ keyimg,    // kslice-major images
    u32* __restrict__ lbuf)
{
  __shared__ u32 kbuf[2][IMG_U32];     // 2 x 20KB
  __shared__ u32 sortbuf[8][128];      // 4KB
  __shared__ float threshL[64];
  __shared__ int cnt[64];
  __shared__ int ovf[2];

  int tid = threadIdx.x;
  int l = tid & 63, w = tid >> 6;
  int l15 = l & 15, l4 = l >> 4;
  int wr = w & 3, wc = w >> 2;         // wr: key quarter, wc: row half
  int slice = blockIdx.x & 7;          // consecutive blocks -> different XCDs
  int rb = (blockIdx.x >> 3) << 6;     // 64 q rows per block

  if (tid < 64) { threshL[tid] = __uint_as_float(0x7F800000u); cnt[tid] = 0; }
  if (tid == 0) { ovf[0] = 0; ovf[1] = 0; }

  // ---- B-frags (q side) in registers for the whole kernel ----
  bf16x8 bfr[4][2];
#pragma unroll
  for (int c = 0; c < 4; ++c)
#pragma unroll
    for (int qf = 0; qf < 2; ++qf) {
      const ushort* qp = qext2 + (size_t)(rb + wc * 32 + qf * 16 + l15) * 128 + c * 32 + l4 * 8;
      bfr[c][qf] = __builtin_bit_cast(bf16x8, *(const u32x4*)qp);
    }
  bf16x8 bk2;
  {
    u16x8 v = {0, 0, 0, 0, 0, 0, 0, 0};
    if (l4 == 0) { v[0] = 0x3F80; v[1] = 0x3F80; }
    bk2 = __builtin_bit_cast(bf16x8, v);
  }
  float q2v[2];
#pragma unroll
  for (int qf = 0; qf < 2; ++qf) q2v[qf] = q2g[rb + wc * 32 + qf * 16 + l15];

  const u32* imgbase = keyimg + (size_t)slice * NB * IMG_U32;

  // stage buffer b with tile t: waves 0-4 issue 4 x global_load_lds_dwordx4 each
  auto stage = [&](int b, int t) {
    if (w < 5) {
      const u32* src = imgbase + (size_t)t * IMG_U32 + w * 1024 + l * 4;
      u32* dst = &kbuf[b][w * 1024];
#pragma unroll
      for (int i = 0; i < 4; ++i)
        gl_lds16(src + i * 256, dst + i * 256);
    }
  };

  stage(0, 0);
  __syncthreads();

  int cur = 0;
  for (int t = 0; t < NB; ++t) {
    if (t + 1 < NB) stage(cur ^ 1, t + 1);   // in flight across compute+selection

    f32x4 acc[2] = {};
#pragma unroll
    for (int c = 0; c < 5; ++c) {
      bf16x8 a = __builtin_bit_cast(bf16x8,
          *(const u32x4*)&kbuf[cur][c * 1024 + l4 * 256 + (wr * 16 + l15) * 4]);
      acc[0] = __builtin_amdgcn_mfma_f32_16x16x32_bf16(a, (c < 4) ? bfr[c][0] : bk2, acc[0], 0, 0, 0);
      acc[1] = __builtin_amdgcn_mfma_f32_16x16x32_bf16(a, (c < 4) ? bfr[c][1] : bk2, acc[1], 0, 0, 0);
    }

    // ---- selection: dd = q2 + (-2*dot + k2) ----
    float ddv[2][4];
    float thF[2];
    thF[0] = threshL[wc * 32 + l15];
    thF[1] = threshL[wc * 32 + 16 + l15];
    u32 pend = 0;
#pragma unroll
    for (int qf = 0; qf < 2; ++qf)
#pragma unroll
      for (int r = 0; r < 4; ++r) {
        float dd = q2v[qf] + acc[qf][r];
        ddv[qf][r] = dd;
        if (dd < thF[qf]) pend |= 1u << ((qf << 2) | r);
      }

    if (pend) {
#pragma unroll
      for (int qf = 0; qf < 2; ++qf) {
        int row = wc * 32 + qf * 16 + l15;
#pragma unroll
        for (int r = 0; r < 4; ++r) {
          u32 bit = 1u << ((qf << 2) | r);
          if (pend & bit) {
            int pos = atomicAdd(&cnt[row], 1);
            if (pos < CAP) {
              int kl = t * BKEY + wr * 16 + (l4 << 2) + r;
              lbuf[(((size_t)(rb + row)) * NSLICE + slice) * CAP + pos] =
                  (__float_as_uint(ddv[qf][r]) & 0xFFFFE000u) | (u32)kl;
              pend &= ~bit;
            } else ovf[cur] = 1;    // benign race
          } else pend &= ~bit;      // no-op, keeps mask tidy
        }
      }
      // restore untested bits cleared above? none: bits not in pend were never set
    }

    __syncthreads();               // ONE barrier: stage drained, kbuf[cur] free, ovf visible

    if (ovf[cur]) {                // rare path
      do {
        compact_block(false, rb, slice, tid, sortbuf, threshL, cnt, lbuf);
        if (tid == 0) ovf[cur] = 0;
        __syncthreads();
        thF[0] = threshL[wc * 32 + l15];
        thF[1] = threshL[wc * 32 + 16 + l15];
        if (pend) {
#pragma unroll
          for (int qf = 0; qf < 2; ++qf) {
            int row = wc * 32 + qf * 16 + l15;
#pragma unroll
            for (int r = 0; r < 4; ++r) {
              u32 bit = 1u << ((qf << 2) | r);
              if (pend & bit) {
                if (ddv[qf][r] < thF[qf]) {
                  int pos = atomicAdd(&cnt[row], 1);
                  if (pos < CAP) {
                    int kl = t * BKEY + wr * 16 + (l4 << 2) + r;
                    lbuf[(((size_t)(rb + row)) * NSLICE + slice) * CAP + pos] =
                        (__float_as_uint(ddv[qf][r]) & 0xFFFFE000u) | (u32)kl;
                    pend &= ~bit;
                  } else ovf[cur] = 1;
                } else pend &= ~bit;
              }
            }
          }
        }
        __syncthreads();
      } while (ovf[cur]);
    }
    cur ^= 1;
  }

  compact_block(true, rb, slice, tid, sortbuf, threshL, cnt, lbuf);
}

// ---------------- K4: merge 8x50 -> approx top-64 -> exact fp32 rerank -> output ------
__global__ __launch_bounds__(256) void k4_rerank(
    const u32* __restrict__ lbuf, const float* __restrict__ qrow,
    const float* __restrict__ q2g, const float* __restrict__ k2g,
    const float* __restrict__ keys, const float* __restrict__ memv,
    const float* __restrict__ net, float* __restrict__ out)
{
  __shared__ u64 sb[512];
  __shared__ float qs[128];
  __shared__ float part[4][RR];
  __shared__ u64 cand[RR];
  int b = blockIdx.x, t = threadIdx.x;
  if (t < 128) qs[t] = qrow[(size_t)b * D_ + t];
#pragma unroll
  for (int h = 0; h < 2; ++h) {
    int e = t + (h << 8);
    u64 v = ~0ull;
    if (e < NSLICE * KNN) {
      int s = e / KNN, j = e - s * KNN;
      u32 k32 = lbuf[((size_t)b * NSLICE + s) * CAP + j];
      v = ((u64)(k32 & 0xFFFFE000u) << 32) | (u32)(s * SL_REAL + (k32 & 0x1FFFu));
    }
    sb[e] = v;
  }
  __syncthreads();
  for (int k = 2; k <= 512; k <<= 1)
    for (int j = k >> 1; j > 0; j >>= 1) {
#pragma unroll
      for (int h = 0; h < 2; ++h) {
        int e = t + (h << 8);
        int p = e ^ j;
        if (p > e) {
          u64 x = sb[e], y = sb[p];
          bool up = ((e & k) == 0);
          if ((x > y) == up) { sb[e] = y; sb[p] = x; }
        }
      }
      __syncthreads();
    }

  // exact rerank of approx-top-RR
  int cid = t & 63, g = t >> 6;
  u32 gidx = (u32)sb[cid];
  const float* kp = keys + (size_t)gidx * D_ + g * 32;
  float dot = 0.f;
#pragma unroll
  for (int i = 0; i < 8; ++i) {
    float4 kv = *(const float4*)(kp + i * 4);
    float4 qv = *(const float4*)&qs[g * 32 + i * 4];
    dot = fmaf(kv.x, qv.x, dot); dot = fmaf(kv.y, qv.y, dot);
    dot = fmaf(kv.z, qv.z, dot); dot = fmaf(kv.w, qv.w, dot);
  }
  part[g][cid] = dot;
  __syncthreads();
  if (t < RR) {
    float dotf = part[0][t] + part[1][t] + part[2][t] + part[3][t];
    u32 gi = (u32)sb[t];
    float dd = q2g[b] + k2g[gi] - 2.0f * dotf;
    cand[t] = ((u64)__float_as_uint(dd) << 32) | gi;
  }
  __syncthreads();
  if (t < 64) {
    for (int k = 2; k <= 64; k <<= 1)
      for (int j = k >> 1; j > 0; j >>= 1) {
        u64 x = cand[t], y = cand[t ^ j];
        __builtin_amdgcn_wave_barrier();
        bool up = ((t & k) == 0);
        u64 mn = x < y ? x : y, mx = x < y ? y : x;
        cand[t] = ((t < (t ^ j)) == up) ? mn : mx;
        __builtin_amdgcn_wave_barrier();
      }
    u64 key = cand[t];
    float d = __uint_as_float((u32)(key >> 32));
    u32 idx = (u32)key;
    float w = 0.f, wv = 0.f;
    if (t < KNN) {
      float ww = 1.0f / (d + 1e-7f);
      w = ww;
      wv = ww * memv[idx];
    }
#pragma unroll
    for (int o = 1; o < 64; o <<= 1) {
      w += __shfl_xor(w, o);
      wv += __shfl_xor(wv, o);
    }
    if (t == 0) out[b] = 0.9f * (wv / w) + 0.1f * net[b];
  }
}

// ---------------- launch --------------------------------------------------------------
extern "C" void kernel_launch(void* const* d_in, const int* in_sizes, int n_in,
                              void* d_out, int out_size, void* d_ws, size_t ws_size,
                              hipStream_t stream)
{
  const float* states     = (const float*)d_in[0];
  const float* W1         = (const float*)d_in[1];
  const float* b1         = (const float*)d_in[2];
  const float* W2         = (const float*)d_in[3];
  const float* b2         = (const float*)d_in[4];
  const float* lng        = (const float*)d_in[5];
  const float* lnb        = (const float*)d_in[6];
  const float* mem_keys   = (const float*)d_in[7];
  const float* mem_values = (const float*)d_in[8];
  const float* V1         = (const float*)d_in[9];
  const float* c1         = (const float*)d_in[10];
  const float* V2         = (const float*)d_in[11];
  const float* c2         = (const float*)d_in[12];
  const float* V3         = (const float*)d_in[13];
  const float* c3         = (const float*)d_in[14];
  float* out = (float*)d_out;

  char* ws = (char*)d_ws;
  ushort* qext2 = (ushort*)(ws + 0);          // 1 MB   [B][128] bf16(-2q)
  float*  qrow  = (float*)(ws + 1048576);     // 2 MB   [B][128] f32
  float*  q2    = (float*)(ws + 3145728);     // 16 KB
  float*  net   = (float*)(ws + 3162112);     // 16 KB
  float*  k2g   = (float*)(ws + 3178496);     // 200 KB (ends 3383296)
  u32*  keyimg  = (u32*)(ws + 3383296);       // 8*98*20KB = 16.06 MB (ends 19,439,616)
  u32*  lbuf    = (u32*)(ws + 19439616);      // 16.78 MB (ends 36,216,832)
  // h / v1 overlay keyimg region: dead before k5 writes it
  float* h  = (float*)(ws + 3383296);             // 4 MB
  float* v1 = (float*)(ws + 3383296 + 4194304);   // 4 MB

  k1_gemm<<<dim3(H_ / 64, B_ / 64, 2), 256, 0, stream>>>(states, W1, b1, V1, c1, h, v1);
  k2_fused<<<dim3(B_ / 32), 256, 0, stream>>>(0, h, W2, b2, lng, lnb, V3, c3, qext2, qrow, q2, net);
  k2_fused<<<dim3(B_ / 32), 256, 0, stream>>>(1, v1, V2, c2, lng, lnb, V3, c3, qext2, qrow, q2, net);
  k5_keyimg<<<dim3(NSLICE * SL_PAD / 128), 256, 0, stream>>>(mem_keys, keyimg, k2g);
  k3_knn<<<dim3((B_ / 64) * NSLICE), 512, 0, stream>>>(qext2, q2, keyimg, lbuf);
  k4_rerank<<<dim3(B_), 256, 0, stream>>>(lbuf, qrow, q2, k2g, mem_keys, mem_values, net, out);
}